// Round 1
// baseline (985.757 us; speedup 1.0000x reference)
//
#include <hip/hip_runtime.h>
#include <math.h>

#define N_NODES 4096
#define BGRAPH  32
#define NEDGE   65536
#define DIM     128
#define NLAYER  4
#define NHEAD   4
#define DHEAD   32

#define TM 64
#define TN 64
#define TK 32

// out[m, n] = sum_k A[m,k] * W[n,k] (+ bias[n]) (+= if accumulate)
__global__ __launch_bounds__(256) void gemm_nt(
    const float* __restrict__ A, const float* __restrict__ W,
    const float* __restrict__ bias, float* __restrict__ out,
    int M, int Ncols, int K, int accumulate)
{
    __shared__ float As[TK][TM];
    __shared__ float Ws[TK][TN];
    int tid = threadIdx.x;
    int bm = blockIdx.x, bn = blockIdx.y;
    int ty = tid >> 4, tx = tid & 15;      // 16x16 thread grid, 4x4 microtile
    int lr = tid >> 2;                     // load row 0..63
    int lc = (tid & 3) * 8;                // load col 0,8,16,24
    float acc[4][4] = {};
    const float* Arow = A + (size_t)(bm * TM + lr) * K;
    const float* Wrow = W + (size_t)(bn * TN + lr) * K;
    for (int kk = 0; kk < K; kk += TK) {
        float4 a0 = *(const float4*)(Arow + kk + lc);
        float4 a1 = *(const float4*)(Arow + kk + lc + 4);
        float4 w0 = *(const float4*)(Wrow + kk + lc);
        float4 w1 = *(const float4*)(Wrow + kk + lc + 4);
        __syncthreads();
        As[lc+0][lr] = a0.x; As[lc+1][lr] = a0.y; As[lc+2][lr] = a0.z; As[lc+3][lr] = a0.w;
        As[lc+4][lr] = a1.x; As[lc+5][lr] = a1.y; As[lc+6][lr] = a1.z; As[lc+7][lr] = a1.w;
        Ws[lc+0][lr] = w0.x; Ws[lc+1][lr] = w0.y; Ws[lc+2][lr] = w0.z; Ws[lc+3][lr] = w0.w;
        Ws[lc+4][lr] = w1.x; Ws[lc+5][lr] = w1.y; Ws[lc+6][lr] = w1.z; Ws[lc+7][lr] = w1.w;
        __syncthreads();
        #pragma unroll
        for (int k = 0; k < TK; ++k) {
            float4 av = *(const float4*)&As[k][ty * 4];
            float4 wv = *(const float4*)&Ws[k][tx * 4];
            acc[0][0] += av.x * wv.x; acc[0][1] += av.x * wv.y; acc[0][2] += av.x * wv.z; acc[0][3] += av.x * wv.w;
            acc[1][0] += av.y * wv.x; acc[1][1] += av.y * wv.y; acc[1][2] += av.y * wv.z; acc[1][3] += av.y * wv.w;
            acc[2][0] += av.z * wv.x; acc[2][1] += av.z * wv.y; acc[2][2] += av.z * wv.z; acc[2][3] += av.z * wv.w;
            acc[3][0] += av.w * wv.x; acc[3][1] += av.w * wv.y; acc[3][2] += av.w * wv.z; acc[3][3] += av.w * wv.w;
        }
    }
    int orow = bm * TM + ty * 4;
    int ocol = bn * TN + tx * 4;
    #pragma unroll
    for (int i = 0; i < 4; ++i) {
        float* op = out + (size_t)(orow + i) * Ncols + ocol;
        #pragma unroll
        for (int j = 0; j < 4; ++j) {
            float v = acc[i][j];
            if (bias) v += bias[ocol + j];
            if (accumulate) op[j] += v; else op[j] = v;
        }
    }
}

__global__ void count_kernel(const int* __restrict__ dst, float* __restrict__ cnt, int E) {
    int e = blockIdx.x * blockDim.x + threadIdx.x;
    if (e < E) atomicAdd(&cnt[dst[e]], 1.0f);
}

__global__ void recip_kernel(float* __restrict__ c, int n) {
    int i = blockIdx.x * blockDim.x + threadIdx.x;
    if (i < n) c[i] = 1.0f / fmaxf(c[i], 1.0f);
}

// agg[dst, d] += ew[e, d] * x[src, d] * recip[dst]
__global__ __launch_bounds__(128) void scatter_kernel(
    const int* __restrict__ src, const int* __restrict__ dst,
    const float* __restrict__ ew, const float* __restrict__ x,
    const float* __restrict__ recip, float* __restrict__ agg)
{
    int e = blockIdx.x;
    int d = threadIdx.x;
    int s = src[e], t = dst[e];
    float r = recip[t];
    atomicAdd(&agg[(size_t)t * DIM + d], ew[(size_t)e * DIM + d] * x[(size_t)s * DIM + d] * r);
}

// One block per (graph, head); thread = q-row; online softmax; block-diagonal mask
__global__ __launch_bounds__(128) void attn_kernel(
    const float* __restrict__ qkv_q, const float* __restrict__ qkv_kv,
    float* __restrict__ o)
{
    int g = blockIdx.x, h = blockIdx.y, t = threadIdx.x;
    __shared__ float k_lds[128][DHEAD];
    __shared__ float v_lds[128][DHEAD];
    const float* kp = qkv_kv + (size_t)(g * 128 + t) * (3 * DIM) + DIM + h * DHEAD;
    const float* vp = kp + DIM;
    #pragma unroll
    for (int j = 0; j < DHEAD; j += 4) {
        *(float4*)&k_lds[t][j] = *(const float4*)(kp + j);
        *(float4*)&v_lds[t][j] = *(const float4*)(vp + j);
    }
    float q[DHEAD];
    const float* qp = qkv_q + (size_t)(g * 128 + t) * (3 * DIM) + h * DHEAD;
    #pragma unroll
    for (int j = 0; j < DHEAD; j += 4) {
        float4 qv = *(const float4*)(qp + j);
        q[j] = qv.x; q[j+1] = qv.y; q[j+2] = qv.z; q[j+3] = qv.w;
    }
    __syncthreads();
    const float scale = 0.17677669529663687f;  // 1/sqrt(32)
    float m = -INFINITY, l = 0.0f;
    float acc[DHEAD];
    #pragma unroll
    for (int j = 0; j < DHEAD; ++j) acc[j] = 0.0f;
    for (int kn = 0; kn < 128; ++kn) {
        float s = 0.0f;
        #pragma unroll
        for (int j4 = 0; j4 < DHEAD; j4 += 4) {
            float4 kv = *(const float4*)&k_lds[kn][j4];
            s += q[j4] * kv.x + q[j4+1] * kv.y + q[j4+2] * kv.z + q[j4+3] * kv.w;
        }
        s *= scale;
        float mn = fmaxf(m, s);
        float c = __expf(m - mn);
        float p = __expf(s - mn);
        l = l * c + p;
        #pragma unroll
        for (int j4 = 0; j4 < DHEAD; j4 += 4) {
            float4 vv = *(const float4*)&v_lds[kn][j4];
            acc[j4]   = acc[j4]   * c + p * vv.x;
            acc[j4+1] = acc[j4+1] * c + p * vv.y;
            acc[j4+2] = acc[j4+2] * c + p * vv.z;
            acc[j4+3] = acc[j4+3] * c + p * vv.w;
        }
        m = mn;
    }
    float inv = 1.0f / l;
    float* op = o + (size_t)(g * 128 + t) * DIM + h * DHEAD;
    #pragma unroll
    for (int j = 0; j < DHEAD; ++j) op[j] = acc[j] * inv;
}

// One wave per row, 2 elems/lane
__global__ __launch_bounds__(256) void ln_kernel(
    const float* __restrict__ in, const float* __restrict__ gamma,
    const float* __restrict__ beta, float* __restrict__ out, int rows)
{
    int wid = threadIdx.x >> 6, lane = threadIdx.x & 63;
    int row = blockIdx.x * 4 + wid;
    if (row >= rows) return;
    const float* xr = in + (size_t)row * DIM;
    float2 v = *(const float2*)(xr + lane * 2);
    float s = v.x + v.y;
    #pragma unroll
    for (int off = 1; off < 64; off <<= 1) s += __shfl_xor(s, off);
    float mu = s * (1.0f / 128.0f);
    float d0 = v.x - mu, d1 = v.y - mu;
    float qv = d0 * d0 + d1 * d1;
    #pragma unroll
    for (int off = 1; off < 64; off <<= 1) qv += __shfl_xor(qv, off);
    float inv = rsqrtf(qv * (1.0f / 128.0f) + 1e-5f);
    float2 gv = *(const float2*)(gamma + lane * 2);
    float2 bv = *(const float2*)(beta + lane * 2);
    float* orow = out + (size_t)row * DIM;
    orow[lane * 2]     = d0 * inv * gv.x + bv.x;
    orow[lane * 2 + 1] = d1 * inv * gv.y + bv.y;
}

// One block per graph (128 contiguous nodes). GlobalAttention pool.
__global__ __launch_bounds__(128) void pool_kernel(
    const float* __restrict__ x, const float* __restrict__ gw,
    const float* __restrict__ gb, float* __restrict__ p)
{
    int g = blockIdx.x, t = threadIdx.x;
    const float* xr = x + (size_t)(g * 128 + t) * DIM;
    float dot = gb[0];
    #pragma unroll
    for (int d = 0; d < DIM; d += 4) {
        float4 xv = *(const float4*)(xr + d);
        float4 wv = *(const float4*)(gw + d);
        dot += xv.x * wv.x + xv.y * wv.y + xv.z * wv.z + xv.w * wv.w;
    }
    float gate = 1.0f / (1.0f + __expf(-dot));
    __shared__ float sm[128];
    __shared__ float al[128];
    sm[t] = gate; __syncthreads();
    for (int s = 64; s > 0; s >>= 1) { if (t < s) sm[t] = fmaxf(sm[t], sm[t + s]); __syncthreads(); }
    float m = sm[0]; __syncthreads();
    float e = __expf(gate - m);
    sm[t] = e; __syncthreads();
    for (int s = 64; s > 0; s >>= 1) { if (t < s) sm[t] += sm[t + s]; __syncthreads(); }
    float z = sm[0]; __syncthreads();
    al[t] = e / z; __syncthreads();
    float acc = 0.0f;
    for (int n = 0; n < 128; ++n) acc += al[n] * x[(size_t)(g * 128 + n) * DIM + t];
    p[(size_t)g * DIM + t] = acc;
}

__global__ __launch_bounds__(64) void cosine_kernel(
    const float* __restrict__ ps, const float* __restrict__ pt, float* __restrict__ out)
{
    int g = blockIdx.x, lane = threadIdx.x;
    float a0 = ps[g * DIM + lane], a1 = ps[g * DIM + 64 + lane];
    float b0 = pt[g * DIM + lane], b1 = pt[g * DIM + 64 + lane];
    float saa = a0 * a0 + a1 * a1;
    float sbb = b0 * b0 + b1 * b1;
    float sab = a0 * b0 + a1 * b1;
    #pragma unroll
    for (int off = 32; off; off >>= 1) {
        saa += __shfl_down(saa, off);
        sbb += __shfl_down(sbb, off);
        sab += __shfl_down(sab, off);
    }
    if (lane == 0) {
        float na = fmaxf(sqrtf(saa), 1e-12f);
        float nb = fmaxf(sqrtf(sbb), 1e-12f);
        out[g] = sab / (na * nb);
    }
}

extern "C" void kernel_launch(void* const* d_in, const int* in_sizes, int n_in,
                              void* d_out, int out_size, void* d_ws, size_t ws_size,
                              hipStream_t stream)
{
    const float* x_s    = (const float*)d_in[0];
    const float* x_t    = (const float*)d_in[1];
    const int*   ei_s   = (const int*)d_in[2];
    const float* ea_s   = (const float*)d_in[3];
    const int*   ei_t   = (const int*)d_in[4];
    const float* ea_t   = (const float*)d_in[5];
    // d_in[6], d_in[7]: batch arrays — contiguous 128-node blocks by construction
    const float* rel_w  = (const float*)d_in[8];
    const float* rel_b  = (const float*)d_in[9];
    const float* root_w = (const float*)d_in[10];
    const float* in_w   = (const float*)d_in[11];
    const float* in_b   = (const float*)d_in[12];
    const float* out_w  = (const float*)d_in[13];
    const float* out_b  = (const float*)d_in[14];
    const float* g_ln   = (const float*)d_in[15];
    const float* b_ln   = (const float*)d_in[16];
    const float* gate_w = (const float*)d_in[17];
    const float* gate_b = (const float*)d_in[18];
    float* out = (float*)d_out;

    const size_t ND = (size_t)N_NODES * DIM;
    float* ws = (float*)d_ws;
    float* xs   = ws; ws += ND;
    float* xt   = ws; ws += ND;
    float* ys   = ws; ws += ND;        // agg (scatter) then out-proj result
    float* yt   = ws; ws += ND;
    float* hs   = ws; ws += ND;
    float* ht   = ws; ws += ND;
    float* qs   = ws; ws += ND * 3;
    float* qt   = ws; ws += ND * 3;
    float* os_  = ws; ws += ND;
    float* ot_  = ws; ws += ND;
    float* recs = ws; ws += N_NODES;
    float* rect = ws; ws += N_NODES;
    float* ps   = ws; ws += (size_t)BGRAPH * DIM;
    float* pt   = ws; ws += (size_t)BGRAPH * DIM;

    const int* src_s = ei_s, *dst_s = ei_s + NEDGE;
    const int* src_t = ei_t, *dst_t = ei_t + NEDGE;

    hipMemcpyAsync(xs, x_s, ND * 4, hipMemcpyDeviceToDevice, stream);
    hipMemcpyAsync(xt, x_t, ND * 4, hipMemcpyDeviceToDevice, stream);
    hipMemsetAsync(recs, 0, N_NODES * 4, stream);
    hipMemsetAsync(rect, 0, N_NODES * 4, stream);
    count_kernel<<<(NEDGE + 255) / 256, 256, 0, stream>>>(dst_s, recs, NEDGE);
    count_kernel<<<(NEDGE + 255) / 256, 256, 0, stream>>>(dst_t, rect, NEDGE);
    recip_kernel<<<(N_NODES + 255) / 256, 256, 0, stream>>>(recs, N_NODES);
    recip_kernel<<<(N_NODES + 255) / 256, 256, 0, stream>>>(rect, N_NODES);

    dim3 g1(N_NODES / TM, DIM / TN);
    dim3 g3(N_NODES / TM, (3 * DIM) / TN);
    dim3 ga(BGRAPH, NHEAD);

    for (int i = 0; i < NLAYER; ++i) {
        const float* wrel  = rel_w  + (size_t)i * DIM * DIM;
        const float* brel  = rel_b  + (size_t)i * DIM;
        const float* wroot = root_w + (size_t)i * DIM * DIM;
        const float* win   = in_w   + (size_t)i * 3 * DIM * DIM;
        const float* bin   = in_b   + (size_t)i * 3 * DIM;
        const float* wout  = out_w  + (size_t)i * DIM * DIM;
        const float* bout  = out_b  + (size_t)i * DIM;
        const float* lg    = g_ln   + (size_t)i * DIM;
        const float* lb    = b_ln   + (size_t)i * DIM;

        hipMemsetAsync(ys, 0, ND * 4, stream);
        hipMemsetAsync(yt, 0, ND * 4, stream);
        scatter_kernel<<<NEDGE, DIM, 0, stream>>>(src_s, dst_s, ea_s, xs, recs, ys);
        scatter_kernel<<<NEDGE, DIM, 0, stream>>>(src_t, dst_t, ea_t, xt, rect, yt);

        gemm_nt<<<g1, 256, 0, stream>>>(xs, wroot, brel, hs, N_NODES, DIM, DIM, 0);
        gemm_nt<<<g1, 256, 0, stream>>>(ys, wrel, nullptr, hs, N_NODES, DIM, DIM, 1);
        gemm_nt<<<g1, 256, 0, stream>>>(xt, wroot, brel, ht, N_NODES, DIM, DIM, 0);
        gemm_nt<<<g1, 256, 0, stream>>>(yt, wrel, nullptr, ht, N_NODES, DIM, DIM, 1);

        gemm_nt<<<g3, 256, 0, stream>>>(hs, win, bin, qs, N_NODES, 3 * DIM, DIM, 0);
        gemm_nt<<<g3, 256, 0, stream>>>(ht, win, bin, qt, N_NODES, 3 * DIM, DIM, 0);

        attn_kernel<<<ga, 128, 0, stream>>>(qs, qt, os_);
        attn_kernel<<<ga, 128, 0, stream>>>(qt, qs, ot_);

        gemm_nt<<<g1, 256, 0, stream>>>(os_, wout, bout, ys, N_NODES, DIM, DIM, 0);
        gemm_nt<<<g1, 256, 0, stream>>>(ot_, wout, bout, yt, N_NODES, DIM, DIM, 0);

        ln_kernel<<<N_NODES / 4, 256, 0, stream>>>(ys, lg, lb, xs, N_NODES);
        ln_kernel<<<N_NODES / 4, 256, 0, stream>>>(yt, lg, lb, xt, N_NODES);
    }

    pool_kernel<<<BGRAPH, 128, 0, stream>>>(xs, gate_w, gate_b, ps);
    pool_kernel<<<BGRAPH, 128, 0, stream>>>(xt, gate_w, gate_b, pt);
    cosine_kernel<<<BGRAPH, 64, 0, stream>>>(ps, pt, out);
}

// Round 2
// 458.444 us; speedup vs baseline: 2.1502x; 2.1502x over previous
//
#include <hip/hip_runtime.h>
#include <math.h>

#define N_NODES 4096
#define NROWS   8192      // both sides stacked
#define BGRAPH  32
#define NEDGE   65536
#define DIM     128
#define NLAYER  4
#define NHEAD   4
#define DHEAD   32

#define TM 64
#define TN 64
#define TK 32

// out[m,n] = sum_k A1[m,k]W1[n,k] (+ sum_k A2[m,k]W2[n,k]) + bias[n]
// A1/A2: [M, K] row-major; W1/W2: [N, K] row-major (torch Linear layout)
__global__ __launch_bounds__(256) void gemm_nt2(
    const float* __restrict__ A1, const float* __restrict__ W1,
    const float* __restrict__ A2, const float* __restrict__ W2,
    const float* __restrict__ bias, float* __restrict__ out,
    int M, int Ncols, int K)
{
    __shared__ float As[TK][TM];
    __shared__ float Ws[TK][TN];
    int tid = threadIdx.x;
    int bm = blockIdx.x, bn = blockIdx.y;
    int ty = tid >> 4, tx = tid & 15;      // 16x16 thread grid, 4x4 microtile
    int lr = tid >> 2;                     // load row 0..63
    int lc = (tid & 3) * 8;                // load col 0,8,16,24
    float acc[4][4] = {};
    int Ktot = A2 ? 2 * K : K;
    for (int kk = 0; kk < Ktot; kk += TK) {
        const float* Abase;
        const float* Wbase;
        int kc;
        if (kk < K) { Abase = A1; Wbase = W1; kc = kk; }
        else        { Abase = A2; Wbase = W2; kc = kk - K; }
        const float* Arow = Abase + (size_t)(bm * TM + lr) * K + kc + lc;
        const float* Wrow = Wbase + (size_t)(bn * TN + lr) * K + kc + lc;
        float4 a0 = *(const float4*)(Arow);
        float4 a1 = *(const float4*)(Arow + 4);
        float4 w0 = *(const float4*)(Wrow);
        float4 w1 = *(const float4*)(Wrow + 4);
        __syncthreads();
        As[lc+0][lr] = a0.x; As[lc+1][lr] = a0.y; As[lc+2][lr] = a0.z; As[lc+3][lr] = a0.w;
        As[lc+4][lr] = a1.x; As[lc+5][lr] = a1.y; As[lc+6][lr] = a1.z; As[lc+7][lr] = a1.w;
        Ws[lc+0][lr] = w0.x; Ws[lc+1][lr] = w0.y; Ws[lc+2][lr] = w0.z; Ws[lc+3][lr] = w0.w;
        Ws[lc+4][lr] = w1.x; Ws[lc+5][lr] = w1.y; Ws[lc+6][lr] = w1.z; Ws[lc+7][lr] = w1.w;
        __syncthreads();
        #pragma unroll
        for (int k = 0; k < TK; ++k) {
            float4 av = *(const float4*)&As[k][ty * 4];
            float4 wv = *(const float4*)&Ws[k][tx * 4];
            acc[0][0] += av.x * wv.x; acc[0][1] += av.x * wv.y; acc[0][2] += av.x * wv.z; acc[0][3] += av.x * wv.w;
            acc[1][0] += av.y * wv.x; acc[1][1] += av.y * wv.y; acc[1][2] += av.y * wv.z; acc[1][3] += av.y * wv.w;
            acc[2][0] += av.z * wv.x; acc[2][1] += av.z * wv.y; acc[2][2] += av.z * wv.z; acc[2][3] += av.z * wv.w;
            acc[3][0] += av.w * wv.x; acc[3][1] += av.w * wv.y; acc[3][2] += av.w * wv.z; acc[3][3] += av.w * wv.w;
        }
    }
    int orow = bm * TM + ty * 4;
    int ocol = bn * TN + tx * 4;
    #pragma unroll
    for (int i = 0; i < 4; ++i) {
        float* op = out + (size_t)(orow + i) * Ncols + ocol;
        #pragma unroll
        for (int j = 0; j < 4; ++j) {
            float v = acc[i][j];
            if (bias) v += bias[ocol + j];
            op[j] = v;
        }
    }
}

// ---- edge counting sort (per side) ----
__global__ __launch_bounds__(256) void hist_kernel(
    const int* __restrict__ dst_s, const int* __restrict__ dst_t, int* __restrict__ cnt)
{
    int e = blockIdx.x * 256 + threadIdx.x;
    int side = blockIdx.y;
    const int* d = side ? dst_t : dst_s;
    atomicAdd(&cnt[side * N_NODES + d[e]], 1);
}

// grid 2 blocks (one per side), 256 threads; exclusive scan of 4096 counts
__global__ __launch_bounds__(256) void scan_kernel(
    const int* __restrict__ cnt, int* __restrict__ row_start, int* __restrict__ cursor)
{
    int side = blockIdx.x;
    int t = threadIdx.x;
    __shared__ int part[256];
    int local[16];
    int s = 0;
    #pragma unroll
    for (int j = 0; j < 16; ++j) { local[j] = cnt[side * N_NODES + t * 16 + j]; s += local[j]; }
    part[t] = s;
    __syncthreads();
    for (int off = 1; off < 256; off <<= 1) {
        int v = (t >= off) ? part[t - off] : 0;
        __syncthreads();
        part[t] += v;
        __syncthreads();
    }
    int run = (t == 0) ? 0 : part[t - 1];
    #pragma unroll
    for (int j = 0; j < 16; ++j) {
        int idx = t * 16 + j;
        row_start[side * (N_NODES + 1) + idx] = run;
        cursor[side * N_NODES + idx] = run;
        run += local[j];
    }
    if (t == 255) row_start[side * (N_NODES + 1) + N_NODES] = run;
}

__global__ __launch_bounds__(256) void reorder_kernel(
    const int* __restrict__ dst_s, const int* __restrict__ dst_t,
    int* __restrict__ cursor, int* __restrict__ eord)
{
    int e = blockIdx.x * 256 + threadIdx.x;
    int side = blockIdx.y;
    const int* d = side ? dst_t : dst_s;
    int pos = atomicAdd(&cursor[side * N_NODES + d[e]], 1);
    eord[side * NEDGE + pos] = e;
}

// CSR mean-aggregate: agg[side*N + n, :] = mean_e ew[e,:] * x[src[e],:]
// one wave per node, 2 dims per lane
__global__ __launch_bounds__(64) void agg_kernel(
    const int* __restrict__ src_s, const int* __restrict__ src_t,
    const float* __restrict__ ea_s, const float* __restrict__ ea_t,
    const int* __restrict__ row_start, const int* __restrict__ eord,
    const float* __restrict__ xbuf, float* __restrict__ agg)
{
    int n = blockIdx.x, side = blockIdx.y;
    int lane = threadIdx.x;
    const int* srcarr = side ? src_t : src_s;
    const float* ew = side ? ea_t : ea_s;
    const float* x = xbuf + (size_t)side * N_NODES * DIM;
    const int* eo = eord + (size_t)side * NEDGE;
    int rs = row_start[side * (N_NODES + 1) + n];
    int re = row_start[side * (N_NODES + 1) + n + 1];
    float2 acc = {0.0f, 0.0f};
    for (int i = rs; i < re; ++i) {
        int e = eo[i];
        int sN = srcarr[e];
        float2 w = *(const float2*)(ew + (size_t)e * DIM + lane * 2);
        float2 xv = *(const float2*)(x + (size_t)sN * DIM + lane * 2);
        acc.x += w.x * xv.x;
        acc.y += w.y * xv.y;
    }
    float scale = 1.0f / (float)max(re - rs, 1);
    float* op = agg + (size_t)(side * N_NODES + n) * DIM + lane * 2;
    op[0] = acc.x * scale;
    op[1] = acc.y * scale;
}

// Attention: grid (graph, head, dir); 256 threads = (key-half, q-row).
// Two-pass (max then exp-sum) per half, LDS merge across halves.
__global__ __launch_bounds__(256) void attn_kernel(
    const float* __restrict__ qkv, float* __restrict__ o)
{
    int g = blockIdx.x, h = blockIdx.y, dir = blockIdx.z;
    int qoff  = dir ? N_NODES : 0;
    int kvoff = dir ? 0 : N_NODES;
    int t = threadIdx.x;
    int row = t & 127;
    int half = t >> 7;
    __shared__ float Klds[128][DHEAD];
    __shared__ float Vlds[128][DHEAD];
    __shared__ float Pm[128], Pl[128];
    __shared__ float Pacc[128][DHEAD];
    // cooperative K/V load: 1024 float4s each
    for (int idx = t; idx < 1024; idx += 256) {
        int r = idx >> 3, c = (idx & 7) * 4;
        const float* base = qkv + (size_t)(kvoff + g * 128 + r) * (3 * DIM) + h * DHEAD + c;
        *(float4*)&Klds[r][c] = *(const float4*)(base + DIM);
        *(float4*)&Vlds[r][c] = *(const float4*)(base + 2 * DIM);
    }
    float q[DHEAD];
    const float* qp = qkv + (size_t)(qoff + g * 128 + row) * (3 * DIM) + h * DHEAD;
    #pragma unroll
    for (int j = 0; j < DHEAD; j += 4) {
        float4 qv = *(const float4*)(qp + j);
        q[j] = qv.x; q[j+1] = qv.y; q[j+2] = qv.z; q[j+3] = qv.w;
    }
    __syncthreads();
    const float scale = 0.17677669529663687f;  // 1/sqrt(32)
    int kn0 = half * 64;
    // pass 1: max over this half's 64 keys (independent dots, cheap max chain)
    float m = -INFINITY;
    for (int kn = kn0; kn < kn0 + 64; ++kn) {
        float s = 0.0f;
        #pragma unroll
        for (int j = 0; j < DHEAD; j += 4) {
            float4 kv = *(const float4*)&Klds[kn][j];
            s += q[j] * kv.x + q[j+1] * kv.y + q[j+2] * kv.z + q[j+3] * kv.w;
        }
        m = fmaxf(m, s * scale);
    }
    // pass 2: exp-sum + PV accumulate (32 independent FMA chains)
    float l = 0.0f;
    float acc[DHEAD];
    #pragma unroll
    for (int j = 0; j < DHEAD; ++j) acc[j] = 0.0f;
    for (int kn = kn0; kn < kn0 + 64; ++kn) {
        float s = 0.0f;
        #pragma unroll
        for (int j = 0; j < DHEAD; j += 4) {
            float4 kv = *(const float4*)&Klds[kn][j];
            s += q[j] * kv.x + q[j+1] * kv.y + q[j+2] * kv.z + q[j+3] * kv.w;
        }
        float p = __expf(s * scale - m);
        l += p;
        #pragma unroll
        for (int j = 0; j < DHEAD; j += 4) {
            float4 vv = *(const float4*)&Vlds[kn][j];
            acc[j]   += p * vv.x;
            acc[j+1] += p * vv.y;
            acc[j+2] += p * vv.z;
            acc[j+3] += p * vv.w;
        }
    }
    // merge halves
    if (half == 1) {
        Pm[row] = m; Pl[row] = l;
        #pragma unroll
        for (int j = 0; j < DHEAD; ++j) Pacc[row][j] = acc[j];
    }
    __syncthreads();
    if (half == 0) {
        float m2 = Pm[row], l2 = Pl[row];
        float mn = fmaxf(m, m2);
        float c1 = __expf(m - mn), c2 = __expf(m2 - mn);
        float linv = 1.0f / (l * c1 + l2 * c2);
        float* op = o + (size_t)(qoff + g * 128 + row) * DIM + h * DHEAD;
        #pragma unroll
        for (int j = 0; j < DHEAD; ++j)
            op[j] = (acc[j] * c1 + Pacc[row][j] * c2) * linv;
    }
}

// One wave per row, 2 elems/lane
__global__ __launch_bounds__(256) void ln_kernel(
    const float* __restrict__ in, const float* __restrict__ gamma,
    const float* __restrict__ beta, float* __restrict__ out, int rows)
{
    int wid = threadIdx.x >> 6, lane = threadIdx.x & 63;
    int row = blockIdx.x * 4 + wid;
    if (row >= rows) return;
    const float* xr = in + (size_t)row * DIM;
    float2 v = *(const float2*)(xr + lane * 2);
    float s = v.x + v.y;
    #pragma unroll
    for (int off = 1; off < 64; off <<= 1) s += __shfl_xor(s, off);
    float mu = s * (1.0f / 128.0f);
    float d0 = v.x - mu, d1 = v.y - mu;
    float qv = d0 * d0 + d1 * d1;
    #pragma unroll
    for (int off = 1; off < 64; off <<= 1) qv += __shfl_xor(qv, off);
    float inv = rsqrtf(qv * (1.0f / 128.0f) + 1e-5f);
    float2 gv = *(const float2*)(gamma + lane * 2);
    float2 bv = *(const float2*)(beta + lane * 2);
    float* orow = out + (size_t)row * DIM;
    orow[lane * 2]     = d0 * inv * gv.x + bv.x;
    orow[lane * 2 + 1] = d1 * inv * gv.y + bv.y;
}

// One block per (graph, side). GlobalAttention pool.
__global__ __launch_bounds__(128) void pool_kernel(
    const float* __restrict__ xbuf, const float* __restrict__ gw,
    const float* __restrict__ gb, float* __restrict__ p)
{
    int g = blockIdx.x, side = blockIdx.y, t = threadIdx.x;
    const float* xr = xbuf + (size_t)(side * N_NODES + g * 128 + t) * DIM;
    float dot = gb[0];
    #pragma unroll
    for (int d = 0; d < DIM; d += 4) {
        float4 xv = *(const float4*)(xr + d);
        float4 wv = *(const float4*)(gw + d);
        dot += xv.x * wv.x + xv.y * wv.y + xv.z * wv.z + xv.w * wv.w;
    }
    float gate = 1.0f / (1.0f + __expf(-dot));
    __shared__ float sm[128];
    __shared__ float al[128];
    sm[t] = gate; __syncthreads();
    for (int s = 64; s > 0; s >>= 1) { if (t < s) sm[t] = fmaxf(sm[t], sm[t + s]); __syncthreads(); }
    float m = sm[0]; __syncthreads();
    float e = __expf(gate - m);
    sm[t] = e; __syncthreads();
    for (int s = 64; s > 0; s >>= 1) { if (t < s) sm[t] += sm[t + s]; __syncthreads(); }
    float z = sm[0]; __syncthreads();
    al[t] = e / z; __syncthreads();
    float acc = 0.0f;
    const float* xg = xbuf + (size_t)(side * N_NODES + g * 128) * DIM;
    for (int n = 0; n < 128; ++n) acc += al[n] * xg[(size_t)n * DIM + t];
    p[(size_t)(side * BGRAPH + g) * DIM + t] = acc;
}

__global__ __launch_bounds__(64) void cosine_kernel(
    const float* __restrict__ p, float* __restrict__ out)
{
    int g = blockIdx.x, lane = threadIdx.x;
    const float* ps = p + (size_t)g * DIM;
    const float* pt = p + (size_t)(BGRAPH + g) * DIM;
    float a0 = ps[lane], a1 = ps[64 + lane];
    float b0 = pt[lane], b1 = pt[64 + lane];
    float saa = a0 * a0 + a1 * a1;
    float sbb = b0 * b0 + b1 * b1;
    float sab = a0 * b0 + a1 * b1;
    #pragma unroll
    for (int off = 32; off; off >>= 1) {
        saa += __shfl_down(saa, off);
        sbb += __shfl_down(sbb, off);
        sab += __shfl_down(sab, off);
    }
    if (lane == 0) {
        float na = fmaxf(sqrtf(saa), 1e-12f);
        float nb = fmaxf(sqrtf(sbb), 1e-12f);
        out[g] = sab / (na * nb);
    }
}

extern "C" void kernel_launch(void* const* d_in, const int* in_sizes, int n_in,
                              void* d_out, int out_size, void* d_ws, size_t ws_size,
                              hipStream_t stream)
{
    const float* x_s    = (const float*)d_in[0];
    const float* x_t    = (const float*)d_in[1];
    const int*   ei_s   = (const int*)d_in[2];
    const float* ea_s   = (const float*)d_in[3];
    const int*   ei_t   = (const int*)d_in[4];
    const float* ea_t   = (const float*)d_in[5];
    const float* rel_w  = (const float*)d_in[8];
    const float* rel_b  = (const float*)d_in[9];
    const float* root_w = (const float*)d_in[10];
    const float* in_w   = (const float*)d_in[11];
    const float* in_b   = (const float*)d_in[12];
    const float* out_w  = (const float*)d_in[13];
    const float* out_b  = (const float*)d_in[14];
    const float* g_ln   = (const float*)d_in[15];
    const float* b_ln   = (const float*)d_in[16];
    const float* gate_w = (const float*)d_in[17];
    const float* gate_b = (const float*)d_in[18];
    float* out = (float*)d_out;

    const size_t ND  = (size_t)N_NODES * DIM;   // one side
    const size_t RD  = (size_t)NROWS * DIM;     // both sides
    float* ws = (float*)d_ws;
    float* xbuf = ws; ws += RD;        // layer input x (both sides)
    float* agg  = ws; ws += RD;        // conv mean aggregate
    float* hbuf = ws; ws += RD;        // conv output
    float* qbuf = ws; ws += RD * 3;    // qkv
    float* obuf = ws; ws += RD;        // attn output
    float* ybuf = ws; ws += RD;        // out-proj output
    float* pbuf = ws; ws += (size_t)2 * BGRAPH * DIM;
    int* iws = (int*)ws;
    int* cnt       = iws; iws += 2 * N_NODES;
    int* cursor    = iws; iws += 2 * N_NODES;
    int* row_start = iws; iws += 2 * (N_NODES + 1);
    int* eord      = iws; iws += 2 * NEDGE;

    const int* src_s = ei_s, *dst_s = ei_s + NEDGE;
    const int* src_t = ei_t, *dst_t = ei_t + NEDGE;

    // stack inputs into xbuf
    hipMemcpyAsync(xbuf,      x_s, ND * 4, hipMemcpyDeviceToDevice, stream);
    hipMemcpyAsync(xbuf + ND, x_t, ND * 4, hipMemcpyDeviceToDevice, stream);

    // edge counting sort (once; reused by all layers)
    hipMemsetAsync(cnt, 0, 2 * N_NODES * 4, stream);
    dim3 ge(NEDGE / 256, 2);
    hist_kernel<<<ge, 256, 0, stream>>>(dst_s, dst_t, cnt);
    scan_kernel<<<2, 256, 0, stream>>>(cnt, row_start, cursor);
    reorder_kernel<<<ge, 256, 0, stream>>>(dst_s, dst_t, cursor, eord);

    dim3 g1(NROWS / TM, DIM / TN);        // 128 x 2
    dim3 g3(NROWS / TM, (3 * DIM) / TN);  // 128 x 6
    dim3 gagg(N_NODES, 2);
    dim3 gattn(BGRAPH, NHEAD, 2);
    dim3 gpool(BGRAPH, 2);

    for (int i = 0; i < NLAYER; ++i) {
        const float* wrel  = rel_w  + (size_t)i * DIM * DIM;
        const float* brel  = rel_b  + (size_t)i * DIM;
        const float* wroot = root_w + (size_t)i * DIM * DIM;
        const float* win   = in_w   + (size_t)i * 3 * DIM * DIM;
        const float* bin   = in_b   + (size_t)i * 3 * DIM;
        const float* wout  = out_w  + (size_t)i * DIM * DIM;
        const float* bout  = out_b  + (size_t)i * DIM;
        const float* lg    = g_ln   + (size_t)i * DIM;
        const float* lb    = b_ln   + (size_t)i * DIM;

        agg_kernel<<<gagg, 64, 0, stream>>>(src_s, src_t, ea_s, ea_t,
                                            row_start, eord, xbuf, agg);
        // h = x @ Wroot^T + agg @ Wrel^T + brel
        gemm_nt2<<<g1, 256, 0, stream>>>(xbuf, wroot, agg, wrel, brel, hbuf,
                                         NROWS, DIM, DIM);
        // qkv = h @ Win^T + bin
        gemm_nt2<<<g3, 256, 0, stream>>>(hbuf, win, nullptr, nullptr, bin, qbuf,
                                         NROWS, 3 * DIM, DIM);
        attn_kernel<<<gattn, 256, 0, stream>>>(qbuf, obuf);
        // y = o @ Wout^T + bout
        gemm_nt2<<<g1, 256, 0, stream>>>(obuf, wout, nullptr, nullptr, bout, ybuf,
                                         NROWS, DIM, DIM);
        ln_kernel<<<NROWS / 4, 256, 0, stream>>>(ybuf, lg, lb, xbuf, NROWS);
    }

    pool_kernel<<<gpool, 128, 0, stream>>>(xbuf, gate_w, gate_b, pbuf);
    cosine_kernel<<<BGRAPH, 64, 0, stream>>>(pbuf, out);
}

// Round 3
// 380.236 us; speedup vs baseline: 2.5925x; 1.2057x over previous
//
#include <hip/hip_runtime.h>
#include <math.h>

#define N_NODES 4096
#define NROWS   8192      // both sides stacked
#define BGRAPH  32
#define NEDGE   65536
#define DIM     128
#define NLAYER  4
#define NHEAD   4
#define DHEAD   32

#define TM 64
#define TN 64
#define TK 32

// out[m,n] = sum_k A1[m,k]W1[n,k] (+ sum_k A2[m,k]W2[n,k]) + bias[n]
__global__ __launch_bounds__(256) void gemm_nt2(
    const float* __restrict__ A1, const float* __restrict__ W1,
    const float* __restrict__ A2, const float* __restrict__ W2,
    const float* __restrict__ bias, float* __restrict__ out,
    int M, int Ncols, int K)
{
    __shared__ float As[TK][TM];
    __shared__ float Ws[TK][TN];
    int tid = threadIdx.x;
    int bm = blockIdx.x, bn = blockIdx.y;
    int ty = tid >> 4, tx = tid & 15;      // 16x16 thread grid, 4x4 microtile
    int lr = tid >> 2;                     // load row 0..63
    int lc = (tid & 3) * 8;                // load col 0,8,16,24
    float acc[4][4] = {};
    int Ktot = A2 ? 2 * K : K;
    for (int kk = 0; kk < Ktot; kk += TK) {
        const float* Abase;
        const float* Wbase;
        int kc;
        if (kk < K) { Abase = A1; Wbase = W1; kc = kk; }
        else        { Abase = A2; Wbase = W2; kc = kk - K; }
        const float* Arow = Abase + (size_t)(bm * TM + lr) * K + kc + lc;
        const float* Wrow = Wbase + (size_t)(bn * TN + lr) * K + kc + lc;
        float4 a0 = *(const float4*)(Arow);
        float4 a1 = *(const float4*)(Arow + 4);
        float4 w0 = *(const float4*)(Wrow);
        float4 w1 = *(const float4*)(Wrow + 4);
        __syncthreads();
        As[lc+0][lr] = a0.x; As[lc+1][lr] = a0.y; As[lc+2][lr] = a0.z; As[lc+3][lr] = a0.w;
        As[lc+4][lr] = a1.x; As[lc+5][lr] = a1.y; As[lc+6][lr] = a1.z; As[lc+7][lr] = a1.w;
        Ws[lc+0][lr] = w0.x; Ws[lc+1][lr] = w0.y; Ws[lc+2][lr] = w0.z; Ws[lc+3][lr] = w0.w;
        Ws[lc+4][lr] = w1.x; Ws[lc+5][lr] = w1.y; Ws[lc+6][lr] = w1.z; Ws[lc+7][lr] = w1.w;
        __syncthreads();
        #pragma unroll
        for (int k = 0; k < TK; ++k) {
            float4 av = *(const float4*)&As[k][ty * 4];
            float4 wv = *(const float4*)&Ws[k][tx * 4];
            acc[0][0] += av.x * wv.x; acc[0][1] += av.x * wv.y; acc[0][2] += av.x * wv.z; acc[0][3] += av.x * wv.w;
            acc[1][0] += av.y * wv.x; acc[1][1] += av.y * wv.y; acc[1][2] += av.y * wv.z; acc[1][3] += av.y * wv.w;
            acc[2][0] += av.z * wv.x; acc[2][1] += av.z * wv.y; acc[2][2] += av.z * wv.z; acc[2][3] += av.z * wv.w;
            acc[3][0] += av.w * wv.x; acc[3][1] += av.w * wv.y; acc[3][2] += av.w * wv.z; acc[3][3] += av.w * wv.w;
        }
    }
    int orow = bm * TM + ty * 4;
    int ocol = bn * TN + tx * 4;
    #pragma unroll
    for (int i = 0; i < 4; ++i) {
        float* op = out + (size_t)(orow + i) * Ncols + ocol;
        #pragma unroll
        for (int j = 0; j < 4; ++j) {
            float v = acc[i][j];
            if (bias) v += bias[ocol + j];
            op[j] = v;
        }
    }
}

// Fused out-proj + LayerNorm. TM=32, TN=128 (block owns full rows).
// out = LN(A @ W^T + bias) * gamma + beta
__global__ __launch_bounds__(256) void gemm_ln(
    const float* __restrict__ A, const float* __restrict__ W,
    const float* __restrict__ bias, const float* __restrict__ gamma,
    const float* __restrict__ beta, float* __restrict__ out)
{
    __shared__ float As[TK][32];
    __shared__ float Ws[TK][128];
    __shared__ float red_s[32][17];
    __shared__ float red_q[32][17];
    int tid = threadIdx.x;
    int bm = blockIdx.x;
    int ty = tid >> 4, tx = tid & 15;      // rows ty*2..+1, cols tx*8..+7
    float acc[2][8] = {};
    int alr = tid >> 3, alc = (tid & 7) * 4;   // A: 32 rows x 32 k, float4
    int wlr = tid >> 1, wlc = (tid & 1) * 16;  // W: 128 rows x 32 k, 4x float4
    for (int kk = 0; kk < DIM; kk += TK) {
        float4 a0 = *(const float4*)(A + (size_t)(bm * 32 + alr) * DIM + kk + alc);
        float4 w0 = *(const float4*)(W + (size_t)wlr * DIM + kk + wlc);
        float4 w1 = *(const float4*)(W + (size_t)wlr * DIM + kk + wlc + 4);
        float4 w2 = *(const float4*)(W + (size_t)wlr * DIM + kk + wlc + 8);
        float4 w3 = *(const float4*)(W + (size_t)wlr * DIM + kk + wlc + 12);
        __syncthreads();
        As[alc+0][alr] = a0.x; As[alc+1][alr] = a0.y; As[alc+2][alr] = a0.z; As[alc+3][alr] = a0.w;
        Ws[wlc+0][wlr] = w0.x; Ws[wlc+1][wlr] = w0.y; Ws[wlc+2][wlr] = w0.z; Ws[wlc+3][wlr] = w0.w;
        Ws[wlc+4][wlr] = w1.x; Ws[wlc+5][wlr] = w1.y; Ws[wlc+6][wlr] = w1.z; Ws[wlc+7][wlr] = w1.w;
        Ws[wlc+8][wlr] = w2.x; Ws[wlc+9][wlr] = w2.y; Ws[wlc+10][wlr] = w2.z; Ws[wlc+11][wlr] = w2.w;
        Ws[wlc+12][wlr] = w3.x; Ws[wlc+13][wlr] = w3.y; Ws[wlc+14][wlr] = w3.z; Ws[wlc+15][wlr] = w3.w;
        __syncthreads();
        #pragma unroll
        for (int k = 0; k < TK; ++k) {
            float a0v = As[k][ty * 2], a1v = As[k][ty * 2 + 1];
            float4 wv0 = *(const float4*)&Ws[k][tx * 8];
            float4 wv1 = *(const float4*)&Ws[k][tx * 8 + 4];
            acc[0][0] += a0v * wv0.x; acc[0][1] += a0v * wv0.y; acc[0][2] += a0v * wv0.z; acc[0][3] += a0v * wv0.w;
            acc[0][4] += a0v * wv1.x; acc[0][5] += a0v * wv1.y; acc[0][6] += a0v * wv1.z; acc[0][7] += a0v * wv1.w;
            acc[1][0] += a1v * wv0.x; acc[1][1] += a1v * wv0.y; acc[1][2] += a1v * wv0.z; acc[1][3] += a1v * wv0.w;
            acc[1][4] += a1v * wv1.x; acc[1][5] += a1v * wv1.y; acc[1][6] += a1v * wv1.z; acc[1][7] += a1v * wv1.w;
        }
    }
    // add bias, per-row partial sums
    int col = tx * 8;
    float bv[8];
    #pragma unroll
    for (int j = 0; j < 8; ++j) bv[j] = bias[col + j];
    float psum[2], psq[2];
    #pragma unroll
    for (int i = 0; i < 2; ++i) {
        float s = 0, q = 0;
        #pragma unroll
        for (int j = 0; j < 8; ++j) {
            float v = acc[i][j] + bv[j];
            acc[i][j] = v;
            s += v; q += v * v;
        }
        psum[i] = s; psq[i] = q;
    }
    __syncthreads();
    #pragma unroll
    for (int i = 0; i < 2; ++i) {
        red_s[ty * 2 + i][tx] = psum[i];
        red_q[ty * 2 + i][tx] = psq[i];
    }
    __syncthreads();
    float gv[8], bt[8];
    #pragma unroll
    for (int j = 0; j < 8; ++j) { gv[j] = gamma[col + j]; bt[j] = beta[col + j]; }
    #pragma unroll
    for (int i = 0; i < 2; ++i) {
        int r = ty * 2 + i;
        float s = 0, q = 0;
        #pragma unroll
        for (int k = 0; k < 16; ++k) { s += red_s[r][k]; q += red_q[r][k]; }
        float mu = s * (1.0f / 128.0f);
        float var = q * (1.0f / 128.0f) - mu * mu;
        float inv = rsqrtf(var + 1e-5f);
        float* op = out + (size_t)(bm * 32 + r) * DIM + col;
        #pragma unroll
        for (int j = 0; j < 8; ++j)
            op[j] = (acc[i][j] - mu) * inv * gv[j] + bt[j];
    }
}

// ---- edge counting sort (per side) ----
__global__ __launch_bounds__(256) void hist_kernel(
    const int* __restrict__ dst_s, const int* __restrict__ dst_t, int* __restrict__ cnt)
{
    int e = blockIdx.x * 256 + threadIdx.x;
    int side = blockIdx.y;
    const int* d = side ? dst_t : dst_s;
    atomicAdd(&cnt[side * N_NODES + d[e]], 1);
}

__global__ __launch_bounds__(256) void scan_kernel(
    const int* __restrict__ cnt, int* __restrict__ row_start, int* __restrict__ cursor)
{
    int side = blockIdx.x;
    int t = threadIdx.x;
    __shared__ int part[256];
    int local[16];
    int s = 0;
    #pragma unroll
    for (int j = 0; j < 16; ++j) { local[j] = cnt[side * N_NODES + t * 16 + j]; s += local[j]; }
    part[t] = s;
    __syncthreads();
    for (int off = 1; off < 256; off <<= 1) {
        int v = (t >= off) ? part[t - off] : 0;
        __syncthreads();
        part[t] += v;
        __syncthreads();
    }
    int run = (t == 0) ? 0 : part[t - 1];
    #pragma unroll
    for (int j = 0; j < 16; ++j) {
        int idx = t * 16 + j;
        row_start[side * (N_NODES + 1) + idx] = run;
        cursor[side * N_NODES + idx] = run;
        run += local[j];
    }
    if (t == 255) row_start[side * (N_NODES + 1) + N_NODES] = run;
}

__global__ __launch_bounds__(256) void reorder_kernel(
    const int* __restrict__ dst_s, const int* __restrict__ dst_t,
    int* __restrict__ cursor, int* __restrict__ eord)
{
    int e = blockIdx.x * 256 + threadIdx.x;
    int side = blockIdx.y;
    const int* d = side ? dst_t : dst_s;
    int pos = atomicAdd(&cursor[side * N_NODES + d[e]], 1);
    eord[side * NEDGE + pos] = e;
}

// CSR mean-aggregate: agg[side*N + n, :] = mean_e ew[e,:] * x[src[e],:]
__global__ __launch_bounds__(64) void agg_kernel(
    const int* __restrict__ src_s, const int* __restrict__ src_t,
    const float* __restrict__ ea_s, const float* __restrict__ ea_t,
    const int* __restrict__ row_start, const int* __restrict__ eord,
    const float* __restrict__ xbuf, float* __restrict__ agg)
{
    int n = blockIdx.x, side = blockIdx.y;
    int lane = threadIdx.x;
    const int* srcarr = side ? src_t : src_s;
    const float* ew = side ? ea_t : ea_s;
    const float* x = xbuf + (size_t)side * N_NODES * DIM;
    const int* eo = eord + (size_t)side * NEDGE;
    int rs = row_start[side * (N_NODES + 1) + n];
    int re = row_start[side * (N_NODES + 1) + n + 1];
    float2 acc = {0.0f, 0.0f};
    for (int i = rs; i < re; ++i) {
        int e = eo[i];
        int sN = srcarr[e];
        float2 w = *(const float2*)(ew + (size_t)e * DIM + lane * 2);
        float2 xv = *(const float2*)(x + (size_t)sN * DIM + lane * 2);
        acc.x += w.x * xv.x;
        acc.y += w.y * xv.y;
    }
    float scale = 1.0f / (float)max(re - rs, 1);
    float* op = agg + (size_t)(side * N_NODES + n) * DIM + lane * 2;
    op[0] = acc.x * scale;
    op[1] = acc.y * scale;
}

// Attention v3: grid (graph, head, dir); 512 threads = (key-quarter, q-row).
// Scores cached in registers; global max known before PV -> no rescale.
__global__ __launch_bounds__(512) void attn_kernel(
    const float* __restrict__ qkv, float* __restrict__ o)
{
    int g = blockIdx.x, h = blockIdx.y, dir = blockIdx.z;
    int qoff  = dir ? N_NODES : 0;
    int kvoff = dir ? 0 : N_NODES;
    int t = threadIdx.x;
    int row = t & 127;
    int qt = t >> 7;                       // key quarter 0..3
    __shared__ float Klds[128][DHEAD];
    __shared__ float Vlds[128][DHEAD];
    __shared__ float Pm[4][128];
    __shared__ float Pl[4][128];
    __shared__ float Pacc[4][128][DHEAD + 1];   // +1 pad: conflict-free
    for (int idx = t; idx < 1024; idx += 512) {
        int r = idx >> 3, c = (idx & 7) * 4;
        const float* base = qkv + (size_t)(kvoff + g * 128 + r) * (3 * DIM) + h * DHEAD + c;
        *(float4*)&Klds[r][c] = *(const float4*)(base + DIM);
        *(float4*)&Vlds[r][c] = *(const float4*)(base + 2 * DIM);
    }
    const float scale = 0.17677669529663687f;  // 1/sqrt(32)
    float q[DHEAD];
    const float* qp = qkv + (size_t)(qoff + g * 128 + row) * (3 * DIM) + h * DHEAD;
    #pragma unroll
    for (int j = 0; j < DHEAD; j += 4) {
        float4 qv = *(const float4*)(qp + j);
        q[j] = qv.x * scale; q[j+1] = qv.y * scale; q[j+2] = qv.z * scale; q[j+3] = qv.w * scale;
    }
    __syncthreads();
    int kn0 = qt * 32;
    float s[32];
    float m = -INFINITY;
    #pragma unroll
    for (int i = 0; i < 32; ++i) {
        float d = 0.0f;
        #pragma unroll
        for (int j = 0; j < DHEAD; j += 4) {
            float4 kv = *(const float4*)&Klds[kn0 + i][j];
            d += q[j] * kv.x + q[j+1] * kv.y + q[j+2] * kv.z + q[j+3] * kv.w;
        }
        s[i] = d;
        m = fmaxf(m, d);
    }
    Pm[qt][row] = m;
    __syncthreads();
    float gm = fmaxf(fmaxf(Pm[0][row], Pm[1][row]), fmaxf(Pm[2][row], Pm[3][row]));
    float l = 0.0f;
    float acc[DHEAD];
    #pragma unroll
    for (int j = 0; j < DHEAD; ++j) acc[j] = 0.0f;
    #pragma unroll
    for (int i = 0; i < 32; ++i) {
        float p = __expf(s[i] - gm);
        l += p;
        #pragma unroll
        for (int j = 0; j < DHEAD; j += 4) {
            float4 vv = *(const float4*)&Vlds[kn0 + i][j];
            acc[j]   += p * vv.x;
            acc[j+1] += p * vv.y;
            acc[j+2] += p * vv.z;
            acc[j+3] += p * vv.w;
        }
    }
    Pl[qt][row] = l;
    #pragma unroll
    for (int j = 0; j < DHEAD; ++j) Pacc[qt][row][j] = acc[j];
    __syncthreads();
    if (qt == 0) {
        float linv = 1.0f / (Pl[0][row] + Pl[1][row] + Pl[2][row] + Pl[3][row]);
        float* op = o + (size_t)(qoff + g * 128 + row) * DIM + h * DHEAD;
        #pragma unroll
        for (int j = 0; j < DHEAD; ++j) {
            float v = Pacc[0][row][j] + Pacc[1][row][j] + Pacc[2][row][j] + Pacc[3][row][j];
            op[j] = v * linv;
        }
    }
}

// Fused GlobalAttention pool (both sides) + cosine. One block per graph.
__global__ __launch_bounds__(256) void poolcos_kernel(
    const float* __restrict__ xbuf, const float* __restrict__ gw,
    const float* __restrict__ gb, float* __restrict__ out)
{
    int g = blockIdx.x, t = threadIdx.x;
    int side = t >> 7, r = t & 127;
    __shared__ float sm[2][128];
    __shared__ float al[2][128];
    __shared__ float pl[2][DIM];
    const float* xr = xbuf + (size_t)(side * N_NODES + g * 128 + r) * DIM;
    float dot = gb[0];
    #pragma unroll
    for (int d = 0; d < DIM; d += 4) {
        float4 xv = *(const float4*)(xr + d);
        float4 wv = *(const float4*)(gw + d);
        dot += xv.x * wv.x + xv.y * wv.y + xv.z * wv.z + xv.w * wv.w;
    }
    float gate = 1.0f / (1.0f + __expf(-dot));
    sm[side][r] = gate; __syncthreads();
    for (int sN = 64; sN > 0; sN >>= 1) {
        if (r < sN) sm[side][r] = fmaxf(sm[side][r], sm[side][r + sN]);
        __syncthreads();
    }
    float m = sm[side][0]; __syncthreads();
    float e = __expf(gate - m);
    sm[side][r] = e; __syncthreads();
    for (int sN = 64; sN > 0; sN >>= 1) {
        if (r < sN) sm[side][r] += sm[side][r + sN];
        __syncthreads();
    }
    al[side][r] = e / sm[side][0];
    __syncthreads();
    // reassign: thread -> (side, dim)
    int d = t & 127;
    float acc = 0.0f;
    const float* xg = xbuf + (size_t)(side * N_NODES + g * 128) * DIM;
    for (int n = 0; n < 128; ++n) acc += al[side][n] * xg[(size_t)n * DIM + d];
    pl[side][d] = acc;
    __syncthreads();
    if (t < 64) {
        float a0 = pl[0][t], a1 = pl[0][64 + t];
        float b0 = pl[1][t], b1 = pl[1][64 + t];
        float saa = a0 * a0 + a1 * a1;
        float sbb = b0 * b0 + b1 * b1;
        float sab = a0 * b0 + a1 * b1;
        #pragma unroll
        for (int off = 32; off; off >>= 1) {
            saa += __shfl_down(saa, off);
            sbb += __shfl_down(sbb, off);
            sab += __shfl_down(sab, off);
        }
        if (t == 0) {
            float na = fmaxf(sqrtf(saa), 1e-12f);
            float nb = fmaxf(sqrtf(sbb), 1e-12f);
            out[g] = sab / (na * nb);
        }
    }
}

extern "C" void kernel_launch(void* const* d_in, const int* in_sizes, int n_in,
                              void* d_out, int out_size, void* d_ws, size_t ws_size,
                              hipStream_t stream)
{
    const float* x_s    = (const float*)d_in[0];
    const float* x_t    = (const float*)d_in[1];
    const int*   ei_s   = (const int*)d_in[2];
    const float* ea_s   = (const float*)d_in[3];
    const int*   ei_t   = (const int*)d_in[4];
    const float* ea_t   = (const float*)d_in[5];
    const float* rel_w  = (const float*)d_in[8];
    const float* rel_b  = (const float*)d_in[9];
    const float* root_w = (const float*)d_in[10];
    const float* in_w   = (const float*)d_in[11];
    const float* in_b   = (const float*)d_in[12];
    const float* out_w  = (const float*)d_in[13];
    const float* out_b  = (const float*)d_in[14];
    const float* g_ln   = (const float*)d_in[15];
    const float* b_ln   = (const float*)d_in[16];
    const float* gate_w = (const float*)d_in[17];
    const float* gate_b = (const float*)d_in[18];
    float* out = (float*)d_out;

    const size_t ND  = (size_t)N_NODES * DIM;
    const size_t RD  = (size_t)NROWS * DIM;
    float* ws = (float*)d_ws;
    float* xbuf = ws; ws += RD;
    float* agg  = ws; ws += RD;
    float* hbuf = ws; ws += RD;
    float* qbuf = ws; ws += RD * 3;
    float* obuf = ws; ws += RD;
    int* iws = (int*)ws;
    int* cnt       = iws; iws += 2 * N_NODES;
    int* cursor    = iws; iws += 2 * N_NODES;
    int* row_start = iws; iws += 2 * (N_NODES + 1);
    int* eord      = iws; iws += 2 * NEDGE;

    const int* src_s = ei_s, *dst_s = ei_s + NEDGE;
    const int* src_t = ei_t, *dst_t = ei_t + NEDGE;

    hipMemcpyAsync(xbuf,      x_s, ND * 4, hipMemcpyDeviceToDevice, stream);
    hipMemcpyAsync(xbuf + ND, x_t, ND * 4, hipMemcpyDeviceToDevice, stream);

    hipMemsetAsync(cnt, 0, 2 * N_NODES * 4, stream);
    dim3 ge(NEDGE / 256, 2);
    hist_kernel<<<ge, 256, 0, stream>>>(dst_s, dst_t, cnt);
    scan_kernel<<<2, 256, 0, stream>>>(cnt, row_start, cursor);
    reorder_kernel<<<ge, 256, 0, stream>>>(dst_s, dst_t, cursor, eord);

    dim3 g1(NROWS / TM, DIM / TN);        // 128 x 2
    dim3 g3(NROWS / TM, (3 * DIM) / TN);  // 128 x 6
    dim3 gagg(N_NODES, 2);
    dim3 gattn(BGRAPH, NHEAD, 2);

    for (int i = 0; i < NLAYER; ++i) {
        const float* wrel  = rel_w  + (size_t)i * DIM * DIM;
        const float* brel  = rel_b  + (size_t)i * DIM;
        const float* wroot = root_w + (size_t)i * DIM * DIM;
        const float* win   = in_w   + (size_t)i * 3 * DIM * DIM;
        const float* bin   = in_b   + (size_t)i * 3 * DIM;
        const float* wout  = out_w  + (size_t)i * DIM * DIM;
        const float* bout  = out_b  + (size_t)i * DIM;
        const float* lg    = g_ln   + (size_t)i * DIM;
        const float* lb    = b_ln   + (size_t)i * DIM;

        agg_kernel<<<gagg, 64, 0, stream>>>(src_s, src_t, ea_s, ea_t,
                                            row_start, eord, xbuf, agg);
        gemm_nt2<<<g1, 256, 0, stream>>>(xbuf, wroot, agg, wrel, brel, hbuf,
                                         NROWS, DIM, DIM);
        gemm_nt2<<<g3, 256, 0, stream>>>(hbuf, win, nullptr, nullptr, bin, qbuf,
                                         NROWS, 3 * DIM, DIM);
        attn_kernel<<<gattn, 512, 0, stream>>>(qbuf, obuf);
        // out-proj + LN fused, writes next-layer x
        gemm_ln<<<NROWS / 32, 256, 0, stream>>>(obuf, wout, bout, lg, lb, xbuf);
    }

    poolcos_kernel<<<BGRAPH, 256, 0, stream>>>(xbuf, gate_w, gate_b, out);
}

// Round 4
// 305.214 us; speedup vs baseline: 3.2297x; 1.2458x over previous
//
#include <hip/hip_runtime.h>
#include <math.h>

#define N_NODES 4096
#define NROWS   8192      // both sides stacked
#define BGRAPH  32
#define NEDGE   65536
#define DIM     128
#define NLAYER  4
#define NHEAD   4
#define DHEAD   32

typedef _Float16 half8v __attribute__((ext_vector_type(8)));
typedef float f32x4 __attribute__((ext_vector_type(4)));

// ---------------- f16 convert (x + all weights), one dispatch ----------------
__global__ __launch_bounds__(256) void cvt_kernel(
    const float* __restrict__ x_s, const float* __restrict__ x_t,
    const float* __restrict__ rel_w, const float* __restrict__ root_w,
    const float* __restrict__ in_w, const float* __restrict__ out_w,
    _Float16* __restrict__ x16, _Float16* __restrict__ rel16,
    _Float16* __restrict__ root16, _Float16* __restrict__ in16,
    _Float16* __restrict__ outw16)
{
    int seg = blockIdx.y;
    const float* src; _Float16* dst; int n;
    if      (seg == 0) { src = x_s;    dst = x16;            n = N_NODES * DIM; }
    else if (seg == 1) { src = x_t;    dst = x16 + N_NODES * DIM; n = N_NODES * DIM; }
    else if (seg == 2) { src = rel_w;  dst = rel16;          n = NLAYER * DIM * DIM; }
    else if (seg == 3) { src = root_w; dst = root16;         n = NLAYER * DIM * DIM; }
    else if (seg == 4) { src = in_w;   dst = in16;           n = NLAYER * 3 * DIM * DIM; }
    else               { src = out_w;  dst = outw16;         n = NLAYER * DIM * DIM; }
    int i = (blockIdx.x * 256 + threadIdx.x) * 4;
    if (i >= n) return;
    float4 v = *(const float4*)(src + i);
    dst[i]   = (_Float16)v.x;
    dst[i+1] = (_Float16)v.y;
    dst[i+2] = (_Float16)v.z;
    dst[i+3] = (_Float16)v.w;
}

// ---------------- MFMA GEMM: out[m,n] = A1@W1^T (+A2@W2^T) + bias ----------------
// A: [M,128] f16 K-contiguous; W: [N,128] f16 K-contiguous. Block 64x64, 4 waves 2x2.
// Fragments load straight from global (16B/lane), no LDS.
__global__ __launch_bounds__(256) void gemm_mfma(
    const _Float16* __restrict__ A1, const _Float16* __restrict__ W1,
    const _Float16* __restrict__ A2, const _Float16* __restrict__ W2,
    const float* __restrict__ bias,
    float* __restrict__ outf, _Float16* __restrict__ outh, int Ncols)
{
    int tid = threadIdx.x;
    int wave = tid >> 6, lane = tid & 63;
    int wm = wave >> 1, wn = wave & 1;
    int row0 = blockIdx.x * 64 + wm * 32;
    int col0 = blockIdx.y * 64 + wn * 32;
    int lr = lane & 15;
    int lk = (lane >> 4) * 8;
    f32x4 zero = {0.f, 0.f, 0.f, 0.f};
    f32x4 acc[2][2] = {{zero, zero}, {zero, zero}};
    int nsrc = A2 ? 2 : 1;
    for (int s = 0; s < nsrc; ++s) {
        const _Float16* A = s ? A2 : A1;
        const _Float16* W = s ? W2 : W1;
        const _Float16* Ap0 = A + (size_t)(row0 + lr) * DIM + lk;
        const _Float16* Ap1 = A + (size_t)(row0 + 16 + lr) * DIM + lk;
        const _Float16* Wp0 = W + (size_t)(col0 + lr) * DIM + lk;
        const _Float16* Wp1 = W + (size_t)(col0 + 16 + lr) * DIM + lk;
        #pragma unroll
        for (int k0 = 0; k0 < DIM; k0 += 32) {
            half8v a0 = *(const half8v*)(Ap0 + k0);
            half8v a1 = *(const half8v*)(Ap1 + k0);
            half8v b0 = *(const half8v*)(Wp0 + k0);
            half8v b1 = *(const half8v*)(Wp1 + k0);
            acc[0][0] = __builtin_amdgcn_mfma_f32_16x16x32_f16(a0, b0, acc[0][0], 0, 0, 0);
            acc[0][1] = __builtin_amdgcn_mfma_f32_16x16x32_f16(a0, b1, acc[0][1], 0, 0, 0);
            acc[1][0] = __builtin_amdgcn_mfma_f32_16x16x32_f16(a1, b0, acc[1][0], 0, 0, 0);
            acc[1][1] = __builtin_amdgcn_mfma_f32_16x16x32_f16(a1, b1, acc[1][1], 0, 0, 0);
        }
    }
    // C/D layout: col = lane&15, row = (lane>>4)*4 + reg  [m89-verified]
    int g4 = (lane >> 4) * 4;
    #pragma unroll
    for (int fc = 0; fc < 2; ++fc) {
        int col = col0 + fc * 16 + lr;
        float bv = bias[col];
        #pragma unroll
        for (int fr = 0; fr < 2; ++fr) {
            int rbase = row0 + fr * 16 + g4;
            #pragma unroll
            for (int j = 0; j < 4; ++j) {
                float v = acc[fr][fc][j] + bv;
                if (outf) outf[(size_t)(rbase + j) * Ncols + col] = v;
                else      outh[(size_t)(rbase + j) * Ncols + col] = (_Float16)v;
            }
        }
    }
}

// ---------------- MFMA GEMM + LayerNorm fused. Block 32 rows x 128 cols, 4 waves 1x4.
__global__ __launch_bounds__(256) void gemm_ln_mfma(
    const _Float16* __restrict__ A, const _Float16* __restrict__ W,
    const float* __restrict__ bias, const float* __restrict__ gamma,
    const float* __restrict__ beta,
    float* __restrict__ outf, _Float16* __restrict__ outh)
{
    int tid = threadIdx.x;
    int wave = tid >> 6, lane = tid & 63;
    int row0 = blockIdx.x * 32;
    int col0 = wave * 32;
    int lr = lane & 15;
    int lk = (lane >> 4) * 8;
    f32x4 zero = {0.f, 0.f, 0.f, 0.f};
    f32x4 acc[2][2] = {{zero, zero}, {zero, zero}};
    const _Float16* Ap0 = A + (size_t)(row0 + lr) * DIM + lk;
    const _Float16* Ap1 = A + (size_t)(row0 + 16 + lr) * DIM + lk;
    const _Float16* Wp0 = W + (size_t)(col0 + lr) * DIM + lk;
    const _Float16* Wp1 = W + (size_t)(col0 + 16 + lr) * DIM + lk;
    #pragma unroll
    for (int k0 = 0; k0 < DIM; k0 += 32) {
        half8v a0 = *(const half8v*)(Ap0 + k0);
        half8v a1 = *(const half8v*)(Ap1 + k0);
        half8v b0 = *(const half8v*)(Wp0 + k0);
        half8v b1 = *(const half8v*)(Wp1 + k0);
        acc[0][0] = __builtin_amdgcn_mfma_f32_16x16x32_f16(a0, b0, acc[0][0], 0, 0, 0);
        acc[0][1] = __builtin_amdgcn_mfma_f32_16x16x32_f16(a0, b1, acc[0][1], 0, 0, 0);
        acc[1][0] = __builtin_amdgcn_mfma_f32_16x16x32_f16(a1, b0, acc[1][0], 0, 0, 0);
        acc[1][1] = __builtin_amdgcn_mfma_f32_16x16x32_f16(a1, b1, acc[1][1], 0, 0, 0);
    }
    int g = lane >> 4;
    float v[2][2][4];
    #pragma unroll
    for (int fc = 0; fc < 2; ++fc) {
        float bv = bias[col0 + fc * 16 + lr];
        #pragma unroll
        for (int fr = 0; fr < 2; ++fr)
            #pragma unroll
            for (int j = 0; j < 4; ++j)
                v[fr][fc][j] = acc[fr][fc][j] + bv;
    }
    // per-row LN: lane holds rows fr*16+g*4+j, cols {col0+lr, col0+16+lr}
    __shared__ float red_s[32][5];
    __shared__ float red_q[32][5];
    float s[2][4], q[2][4];
    #pragma unroll
    for (int fr = 0; fr < 2; ++fr)
        #pragma unroll
        for (int j = 0; j < 4; ++j) {
            float ss = v[fr][0][j] + v[fr][1][j];
            float qq = v[fr][0][j] * v[fr][0][j] + v[fr][1][j] * v[fr][1][j];
            #pragma unroll
            for (int m = 1; m < 16; m <<= 1) {
                ss += __shfl_xor(ss, m);
                qq += __shfl_xor(qq, m);
            }
            s[fr][j] = ss; q[fr][j] = qq;
        }
    if (lr == 0) {
        #pragma unroll
        for (int fr = 0; fr < 2; ++fr)
            #pragma unroll
            for (int j = 0; j < 4; ++j) {
                red_s[fr * 16 + g * 4 + j][wave] = s[fr][j];
                red_q[fr * 16 + g * 4 + j][wave] = q[fr][j];
            }
    }
    __syncthreads();
    #pragma unroll
    for (int fr = 0; fr < 2; ++fr)
        #pragma unroll
        for (int j = 0; j < 4; ++j) {
            int r = fr * 16 + g * 4 + j;
            float S = red_s[r][0] + red_s[r][1] + red_s[r][2] + red_s[r][3];
            float Q = red_q[r][0] + red_q[r][1] + red_q[r][2] + red_q[r][3];
            float mu = S * (1.0f / 128.0f);
            float inv = rsqrtf(Q * (1.0f / 128.0f) - mu * mu + 1e-5f);
            #pragma unroll
            for (int fc = 0; fc < 2; ++fc) {
                int col = col0 + fc * 16 + lr;
                float o = (v[fr][fc][j] - mu) * inv * gamma[col] + beta[col];
                outf[(size_t)(row0 + r) * DIM + col] = o;
                outh[(size_t)(row0 + r) * DIM + col] = (_Float16)o;
            }
        }
}

// ---------------- edge counting sort (per side) ----------------
__global__ __launch_bounds__(256) void hist_kernel(
    const int* __restrict__ dst_s, const int* __restrict__ dst_t, int* __restrict__ cnt)
{
    int e = blockIdx.x * 256 + threadIdx.x;
    int side = blockIdx.y;
    const int* d = side ? dst_t : dst_s;
    atomicAdd(&cnt[side * N_NODES + d[e]], 1);
}

__global__ __launch_bounds__(256) void scan_kernel(
    const int* __restrict__ cnt, int* __restrict__ row_start, int* __restrict__ cursor)
{
    int side = blockIdx.x;
    int t = threadIdx.x;
    __shared__ int part[256];
    int local[16];
    int s = 0;
    #pragma unroll
    for (int j = 0; j < 16; ++j) { local[j] = cnt[side * N_NODES + t * 16 + j]; s += local[j]; }
    part[t] = s;
    __syncthreads();
    for (int off = 1; off < 256; off <<= 1) {
        int v = (t >= off) ? part[t - off] : 0;
        __syncthreads();
        part[t] += v;
        __syncthreads();
    }
    int run = (t == 0) ? 0 : part[t - 1];
    #pragma unroll
    for (int j = 0; j < 16; ++j) {
        int idx = t * 16 + j;
        row_start[side * (N_NODES + 1) + idx] = run;
        cursor[side * N_NODES + idx] = run;
        run += local[j];
    }
    if (t == 255) row_start[side * (N_NODES + 1) + N_NODES] = run;
}

__global__ __launch_bounds__(256) void reorder_kernel(
    const int* __restrict__ dst_s, const int* __restrict__ dst_t,
    int* __restrict__ cursor, int* __restrict__ eord)
{
    int e = blockIdx.x * 256 + threadIdx.x;
    int side = blockIdx.y;
    const int* d = side ? dst_t : dst_s;
    int pos = atomicAdd(&cursor[side * N_NODES + d[e]], 1);
    eord[side * NEDGE + pos] = e;
}

// CSR mean-aggregate: agg16[side*N+n,:] = (f16) mean_e ew[e,:] * x[src[e],:]
__global__ __launch_bounds__(64) void agg_kernel(
    const int* __restrict__ src_s, const int* __restrict__ src_t,
    const float* __restrict__ ea_s, const float* __restrict__ ea_t,
    const int* __restrict__ row_start, const int* __restrict__ eord,
    const float* __restrict__ xbuf, _Float16* __restrict__ agg16)
{
    int n = blockIdx.x, side = blockIdx.y;
    int lane = threadIdx.x;
    const int* srcarr = side ? src_t : src_s;
    const float* ew = side ? ea_t : ea_s;
    const float* x = xbuf + (size_t)side * N_NODES * DIM;
    const int* eo = eord + (size_t)side * NEDGE;
    int rs = row_start[side * (N_NODES + 1) + n];
    int re = row_start[side * (N_NODES + 1) + n + 1];
    float2 acc = {0.0f, 0.0f};
    for (int i = rs; i < re; ++i) {
        int e = eo[i];
        int sN = srcarr[e];
        float2 w = *(const float2*)(ew + (size_t)e * DIM + lane * 2);
        float2 xv = *(const float2*)(x + (size_t)sN * DIM + lane * 2);
        acc.x += w.x * xv.x;
        acc.y += w.y * xv.y;
    }
    float scale = 1.0f / (float)max(re - rs, 1);
    _Float16* op = agg16 + (size_t)(side * N_NODES + n) * DIM + lane * 2;
    op[0] = (_Float16)(acc.x * scale);
    op[1] = (_Float16)(acc.y * scale);
}

// Attention: grid (graph, head, dir); 512 threads = (key-quarter, q-row).
// Scores cached in registers; global max before PV -> no rescale. f16 output.
__global__ __launch_bounds__(512) void attn_kernel(
    const float* __restrict__ qkv, _Float16* __restrict__ o16)
{
    int g = blockIdx.x, h = blockIdx.y, dir = blockIdx.z;
    int qoff  = dir ? N_NODES : 0;
    int kvoff = dir ? 0 : N_NODES;
    int t = threadIdx.x;
    int row = t & 127;
    int qt = t >> 7;                       // key quarter 0..3
    __shared__ float Klds[128][DHEAD];
    __shared__ float Vlds[128][DHEAD];
    __shared__ float Pm[4][128];
    __shared__ float Pl[4][128];
    __shared__ float Pacc[4][128][DHEAD + 1];
    for (int idx = t; idx < 1024; idx += 512) {
        int r = idx >> 3, c = (idx & 7) * 4;
        const float* base = qkv + (size_t)(kvoff + g * 128 + r) * (3 * DIM) + h * DHEAD + c;
        *(float4*)&Klds[r][c] = *(const float4*)(base + DIM);
        *(float4*)&Vlds[r][c] = *(const float4*)(base + 2 * DIM);
    }
    const float scale = 0.17677669529663687f;  // 1/sqrt(32)
    float q[DHEAD];
    const float* qp = qkv + (size_t)(qoff + g * 128 + row) * (3 * DIM) + h * DHEAD;
    #pragma unroll
    for (int j = 0; j < DHEAD; j += 4) {
        float4 qv = *(const float4*)(qp + j);
        q[j] = qv.x * scale; q[j+1] = qv.y * scale; q[j+2] = qv.z * scale; q[j+3] = qv.w * scale;
    }
    __syncthreads();
    int kn0 = qt * 32;
    float s[32];
    float m = -INFINITY;
    #pragma unroll
    for (int i = 0; i < 32; ++i) {
        float d = 0.0f;
        #pragma unroll
        for (int j = 0; j < DHEAD; j += 4) {
            float4 kv = *(const float4*)&Klds[kn0 + i][j];
            d += q[j] * kv.x + q[j+1] * kv.y + q[j+2] * kv.z + q[j+3] * kv.w;
        }
        s[i] = d;
        m = fmaxf(m, d);
    }
    Pm[qt][row] = m;
    __syncthreads();
    float gm = fmaxf(fmaxf(Pm[0][row], Pm[1][row]), fmaxf(Pm[2][row], Pm[3][row]));
    float l = 0.0f;
    float acc[DHEAD];
    #pragma unroll
    for (int j = 0; j < DHEAD; ++j) acc[j] = 0.0f;
    #pragma unroll
    for (int i = 0; i < 32; ++i) {
        float p = __expf(s[i] - gm);
        l += p;
        #pragma unroll
        for (int j = 0; j < DHEAD; j += 4) {
            float4 vv = *(const float4*)&Vlds[kn0 + i][j];
            acc[j]   += p * vv.x;
            acc[j+1] += p * vv.y;
            acc[j+2] += p * vv.z;
            acc[j+3] += p * vv.w;
        }
    }
    Pl[qt][row] = l;
    #pragma unroll
    for (int j = 0; j < DHEAD; ++j) Pacc[qt][row][j] = acc[j];
    __syncthreads();
    if (qt == 0) {
        float linv = 1.0f / (Pl[0][row] + Pl[1][row] + Pl[2][row] + Pl[3][row]);
        _Float16* op = o16 + (size_t)(qoff + g * 128 + row) * DIM + h * DHEAD;
        #pragma unroll
        for (int j = 0; j < DHEAD; ++j) {
            float v = Pacc[0][row][j] + Pacc[1][row][j] + Pacc[2][row][j] + Pacc[3][row][j];
            op[j] = (_Float16)(v * linv);
        }
    }
}

// Fused GlobalAttention pool (both sides) + cosine. One block per graph.
__global__ __launch_bounds__(256) void poolcos_kernel(
    const float* __restrict__ xbuf, const float* __restrict__ gw,
    const float* __restrict__ gb, float* __restrict__ out)
{
    int g = blockIdx.x, t = threadIdx.x;
    int side = t >> 7, r = t & 127;
    __shared__ float sm[2][128];
    __shared__ float al[2][128];
    __shared__ float pl[2][DIM];
    const float* xr = xbuf + (size_t)(side * N_NODES + g * 128 + r) * DIM;
    float dot = gb[0];
    #pragma unroll
    for (int d = 0; d < DIM; d += 4) {
        float4 xv = *(const float4*)(xr + d);
        float4 wv = *(const float4*)(gw + d);
        dot += xv.x * wv.x + xv.y * wv.y + xv.z * wv.z + xv.w * wv.w;
    }
    float gate = 1.0f / (1.0f + __expf(-dot));
    sm[side][r] = gate; __syncthreads();
    for (int sN = 64; sN > 0; sN >>= 1) {
        if (r < sN) sm[side][r] = fmaxf(sm[side][r], sm[side][r + sN]);
        __syncthreads();
    }
    float m = sm[side][0]; __syncthreads();
    float e = __expf(gate - m);
    sm[side][r] = e; __syncthreads();
    for (int sN = 64; sN > 0; sN >>= 1) {
        if (r < sN) sm[side][r] += sm[side][r + sN];
        __syncthreads();
    }
    al[side][r] = e / sm[side][0];
    __syncthreads();
    int d = t & 127;
    float acc = 0.0f;
    const float* xg = xbuf + (size_t)(side * N_NODES + g * 128) * DIM;
    for (int n = 0; n < 128; ++n) acc += al[side][n] * xg[(size_t)n * DIM + d];
    pl[side][d] = acc;
    __syncthreads();
    if (t < 64) {
        float a0 = pl[0][t], a1 = pl[0][64 + t];
        float b0 = pl[1][t], b1 = pl[1][64 + t];
        float saa = a0 * a0 + a1 * a1;
        float sbb = b0 * b0 + b1 * b1;
        float sab = a0 * b0 + a1 * b1;
        #pragma unroll
        for (int off = 32; off; off >>= 1) {
            saa += __shfl_down(saa, off);
            sbb += __shfl_down(sbb, off);
            sab += __shfl_down(sab, off);
        }
        if (t == 0) {
            float na = fmaxf(sqrtf(saa), 1e-12f);
            float nb = fmaxf(sqrtf(sbb), 1e-12f);
            out[g] = sab / (na * nb);
        }
    }
}

extern "C" void kernel_launch(void* const* d_in, const int* in_sizes, int n_in,
                              void* d_out, int out_size, void* d_ws, size_t ws_size,
                              hipStream_t stream)
{
    const float* x_s    = (const float*)d_in[0];
    const float* x_t    = (const float*)d_in[1];
    const int*   ei_s   = (const int*)d_in[2];
    const float* ea_s   = (const float*)d_in[3];
    const int*   ei_t   = (const int*)d_in[4];
    const float* ea_t   = (const float*)d_in[5];
    const float* rel_w  = (const float*)d_in[8];
    const float* rel_b  = (const float*)d_in[9];
    const float* root_w = (const float*)d_in[10];
    const float* in_w   = (const float*)d_in[11];
    const float* in_b   = (const float*)d_in[12];
    const float* out_w  = (const float*)d_in[13];
    const float* out_b  = (const float*)d_in[14];
    const float* g_ln   = (const float*)d_in[15];
    const float* b_ln   = (const float*)d_in[16];
    const float* gate_w = (const float*)d_in[17];
    const float* gate_b = (const float*)d_in[18];
    float* out = (float*)d_out;

    const size_t ND = (size_t)N_NODES * DIM;
    const size_t RD = (size_t)NROWS * DIM;
    float* ws = (float*)d_ws;
    float* xbuf = ws; ws += RD;        // fp32 x (agg gather + pool)
    float* qbuf = ws; ws += RD * 3;    // fp32 qkv (attn)
    _Float16* h16 = (_Float16*)ws;
    _Float16* x16    = h16; h16 += RD;        // f16 x (conv A1)
    _Float16* agg16  = h16; h16 += RD;        // f16 agg (conv A2)
    _Float16* hb16   = h16; h16 += RD;        // f16 conv out (qkv A)
    _Float16* o16    = h16; h16 += RD;        // f16 attn out (out-proj A)
    _Float16* rel16  = h16; h16 += (size_t)NLAYER * DIM * DIM;
    _Float16* root16 = h16; h16 += (size_t)NLAYER * DIM * DIM;
    _Float16* in16   = h16; h16 += (size_t)NLAYER * 3 * DIM * DIM;
    _Float16* outw16 = h16; h16 += (size_t)NLAYER * DIM * DIM;
    int* iws = (int*)h16;
    int* cnt       = iws; iws += 2 * N_NODES;
    int* cursor    = iws; iws += 2 * N_NODES;
    int* row_start = iws; iws += 2 * (N_NODES + 1);
    int* eord      = iws; iws += 2 * NEDGE;

    const int* src_s = ei_s, *dst_s = ei_s + NEDGE;
    const int* src_t = ei_t, *dst_t = ei_t + NEDGE;

    hipMemcpyAsync(xbuf,      x_s, ND * 4, hipMemcpyDeviceToDevice, stream);
    hipMemcpyAsync(xbuf + ND, x_t, ND * 4, hipMemcpyDeviceToDevice, stream);

    // f16 conversions: x (both sides) + all stacked weights, one dispatch
    {
        dim3 gc(512, 6);
        cvt_kernel<<<gc, 256, 0, stream>>>(x_s, x_t, rel_w, root_w, in_w, out_w,
                                           x16, rel16, root16, in16, outw16);
    }

    // edge counting sort (reused by all layers)
    hipMemsetAsync(cnt, 0, 2 * N_NODES * 4, stream);
    dim3 ge(NEDGE / 256, 2);
    hist_kernel<<<ge, 256, 0, stream>>>(dst_s, dst_t, cnt);
    scan_kernel<<<2, 256, 0, stream>>>(cnt, row_start, cursor);
    reorder_kernel<<<ge, 256, 0, stream>>>(dst_s, dst_t, cursor, eord);

    dim3 g1(NROWS / 64, DIM / 64);        // 128 x 2
    dim3 g3(NROWS / 64, (3 * DIM) / 64);  // 128 x 6
    dim3 gagg(N_NODES, 2);
    dim3 gattn(BGRAPH, NHEAD, 2);

    for (int i = 0; i < NLAYER; ++i) {
        const _Float16* wrel  = rel16  + (size_t)i * DIM * DIM;
        const float*    brel  = rel_b  + (size_t)i * DIM;
        const _Float16* wroot = root16 + (size_t)i * DIM * DIM;
        const _Float16* win   = in16   + (size_t)i * 3 * DIM * DIM;
        const float*    bin   = in_b   + (size_t)i * 3 * DIM;
        const _Float16* wout  = outw16 + (size_t)i * DIM * DIM;
        const float*    bout  = out_b  + (size_t)i * DIM;
        const float*    lg    = g_ln   + (size_t)i * DIM;
        const float*    lb    = b_ln   + (size_t)i * DIM;

        agg_kernel<<<gagg, 64, 0, stream>>>(src_s, src_t, ea_s, ea_t,
                                            row_start, eord, xbuf, agg16);
        // h = x @ Wroot^T + agg @ Wrel^T + brel   (f16 out)
        gemm_mfma<<<g1, 256, 0, stream>>>(x16, wroot, agg16, wrel, brel,
                                          nullptr, hb16, DIM);
        // qkv = h @ Win^T + bin                   (fp32 out for attn)
        gemm_mfma<<<g3, 256, 0, stream>>>(hb16, win, nullptr, nullptr, bin,
                                          qbuf, nullptr, 3 * DIM);
        attn_kernel<<<gattn, 512, 0, stream>>>(qbuf, o16);
        // x = LN(o @ Wout^T + bout)               (fp32 + f16 out)
        gemm_ln_mfma<<<NROWS / 32, 256, 0, stream>>>(o16, wout, bout, lg, lb,
                                                     xbuf, x16);
    }

    poolcos_kernel<<<BGRAPH, 256, 0, stream>>>(xbuf, gate_w, gate_b, out);
}

// Round 5
// 296.933 us; speedup vs baseline: 3.3198x; 1.0279x over previous
//
#include <hip/hip_runtime.h>
#include <math.h>

#define N_NODES 4096
#define NROWS   8192      // both sides stacked
#define BGRAPH  32
#define NEDGE   65536
#define DIM     128
#define NLAYER  4
#define NHEAD   4
#define DHEAD   32

typedef _Float16 half8v __attribute__((ext_vector_type(8)));
typedef float f32x4 __attribute__((ext_vector_type(4)));

// ---------------- f16 convert (x + all weights), one dispatch ----------------
__global__ __launch_bounds__(256) void cvt_kernel(
    const float* __restrict__ x_s, const float* __restrict__ x_t,
    const float* __restrict__ rel_w, const float* __restrict__ root_w,
    const float* __restrict__ in_w, const float* __restrict__ out_w,
    _Float16* __restrict__ x16, _Float16* __restrict__ rel16,
    _Float16* __restrict__ root16, _Float16* __restrict__ in16,
    _Float16* __restrict__ outw16)
{
    int seg = blockIdx.y;
    const float* src; _Float16* dst; int n;
    if      (seg == 0) { src = x_s;    dst = x16;            n = N_NODES * DIM; }
    else if (seg == 1) { src = x_t;    dst = x16 + N_NODES * DIM; n = N_NODES * DIM; }
    else if (seg == 2) { src = rel_w;  dst = rel16;          n = NLAYER * DIM * DIM; }
    else if (seg == 3) { src = root_w; dst = root16;         n = NLAYER * DIM * DIM; }
    else if (seg == 4) { src = in_w;   dst = in16;           n = NLAYER * 3 * DIM * DIM; }
    else               { src = out_w;  dst = outw16;         n = NLAYER * DIM * DIM; }
    int i = (blockIdx.x * 256 + threadIdx.x) * 4;
    if (i >= n) return;
    float4 v = *(const float4*)(src + i);
    dst[i]   = (_Float16)v.x;
    dst[i+1] = (_Float16)v.y;
    dst[i+2] = (_Float16)v.z;
    dst[i+3] = (_Float16)v.w;
}

// ---------------- edge counting sort (per side) ----------------
__global__ __launch_bounds__(256) void hist_kernel(
    const int* __restrict__ dst_s, const int* __restrict__ dst_t, int* __restrict__ cnt)
{
    int e = blockIdx.x * 256 + threadIdx.x;
    int side = blockIdx.y;
    const int* d = side ? dst_t : dst_s;
    atomicAdd(&cnt[side * N_NODES + d[e]], 1);
}

__global__ __launch_bounds__(256) void scan_kernel(
    const int* __restrict__ cnt, int* __restrict__ row_start, int* __restrict__ cursor)
{
    int side = blockIdx.x;
    int t = threadIdx.x;
    __shared__ int part[256];
    int local[16];
    int s = 0;
    #pragma unroll
    for (int j = 0; j < 16; ++j) { local[j] = cnt[side * N_NODES + t * 16 + j]; s += local[j]; }
    part[t] = s;
    __syncthreads();
    for (int off = 1; off < 256; off <<= 1) {
        int v = (t >= off) ? part[t - off] : 0;
        __syncthreads();
        part[t] += v;
        __syncthreads();
    }
    int run = (t == 0) ? 0 : part[t - 1];
    #pragma unroll
    for (int j = 0; j < 16; ++j) {
        int idx = t * 16 + j;
        row_start[side * (N_NODES + 1) + idx] = run;
        cursor[side * N_NODES + idx] = run;
        run += local[j];
    }
    if (t == 255) row_start[side * (N_NODES + 1) + N_NODES] = run;
}

__global__ __launch_bounds__(256) void reorder_kernel(
    const int* __restrict__ dst_s, const int* __restrict__ dst_t,
    int* __restrict__ cursor, int* __restrict__ eord)
{
    int e = blockIdx.x * 256 + threadIdx.x;
    int side = blockIdx.y;
    const int* d = side ? dst_t : dst_s;
    int pos = atomicAdd(&cursor[side * N_NODES + d[e]], 1);
    eord[side * NEDGE + pos] = e;
}

// ---------------- Fused graph-conv: agg (CSR mean, LDS) + dual MFMA GEMM ----
// Block = 32 output rows x 128 cols. h = x@Wroot^T + mean_agg@Wrel^T + brel.
__global__ __launch_bounds__(256) void convagg_kernel(
    const int* __restrict__ src_s, const int* __restrict__ src_t,
    const float* __restrict__ ea_s, const float* __restrict__ ea_t,
    const int* __restrict__ row_start, const int* __restrict__ eord,
    const _Float16* __restrict__ x16,
    const _Float16* __restrict__ wroot, const _Float16* __restrict__ wrel,
    const float* __restrict__ brel,
    _Float16* __restrict__ h16)
{
    int r0 = blockIdx.x * 32;
    int side = (r0 >= N_NODES) ? 1 : 0;
    int nloc = r0 - side * N_NODES;
    __shared__ _Float16 aggl[32][DIM + 8];   // +8 halves: breaks 256B bank alias
    int t = threadIdx.x;
    {
        int rr = t >> 3;                     // row within block
        int qq = t & 7;                      // dim group: [qq*16, qq*16+16)
        int n = nloc + rr;
        const int* srcarr = side ? src_t : src_s;
        const float* ew = side ? ea_t : ea_s;
        const int* eo = eord + side * NEDGE;
        const _Float16* xs = x16 + (size_t)side * N_NODES * DIM;
        int rs = row_start[side * (N_NODES + 1) + n];
        int re = row_start[side * (N_NODES + 1) + n + 1];
        float acc[16] = {};
        for (int i = rs; i < re; ++i) {
            int e = eo[i];
            int sn = srcarr[e];
            const float* ewp = ew + (size_t)e * DIM + qq * 16;
            const _Float16* xp = xs + (size_t)sn * DIM + qq * 16;
            half8v xv0 = *(const half8v*)(xp);
            half8v xv1 = *(const half8v*)(xp + 8);
            float4 w0 = *(const float4*)(ewp);
            float4 w1 = *(const float4*)(ewp + 4);
            float4 w2 = *(const float4*)(ewp + 8);
            float4 w3 = *(const float4*)(ewp + 12);
            acc[0]  += w0.x * (float)xv0[0]; acc[1]  += w0.y * (float)xv0[1];
            acc[2]  += w0.z * (float)xv0[2]; acc[3]  += w0.w * (float)xv0[3];
            acc[4]  += w1.x * (float)xv0[4]; acc[5]  += w1.y * (float)xv0[5];
            acc[6]  += w1.z * (float)xv0[6]; acc[7]  += w1.w * (float)xv0[7];
            acc[8]  += w2.x * (float)xv1[0]; acc[9]  += w2.y * (float)xv1[1];
            acc[10] += w2.z * (float)xv1[2]; acc[11] += w2.w * (float)xv1[3];
            acc[12] += w3.x * (float)xv1[4]; acc[13] += w3.y * (float)xv1[5];
            acc[14] += w3.z * (float)xv1[6]; acc[15] += w3.w * (float)xv1[7];
        }
        float sc = 1.0f / (float)max(re - rs, 1);
        #pragma unroll
        for (int j = 0; j < 16; ++j)
            aggl[rr][qq * 16 + j] = (_Float16)(acc[j] * sc);
    }
    __syncthreads();
    // dual-source GEMM: 4 waves, wave w -> cols [w*32, w*32+32)
    int wave = t >> 6, lane = t & 63;
    int lr = lane & 15, lk = (lane >> 4) * 8;
    int col0 = wave * 32;
    f32x4 zero = {0.f, 0.f, 0.f, 0.f};
    f32x4 acc2[2][2] = {{zero, zero}, {zero, zero}};
    const _Float16* Ap0 = x16 + (size_t)(r0 + lr) * DIM + lk;
    const _Float16* Ap1 = x16 + (size_t)(r0 + 16 + lr) * DIM + lk;
    const _Float16* Wr0 = wroot + (size_t)(col0 + lr) * DIM + lk;
    const _Float16* Wr1 = wroot + (size_t)(col0 + 16 + lr) * DIM + lk;
    const _Float16* We0 = wrel + (size_t)(col0 + lr) * DIM + lk;
    const _Float16* We1 = wrel + (size_t)(col0 + 16 + lr) * DIM + lk;
    #pragma unroll
    for (int k0 = 0; k0 < DIM; k0 += 32) {
        half8v a0 = *(const half8v*)(Ap0 + k0);
        half8v a1 = *(const half8v*)(Ap1 + k0);
        half8v b0 = *(const half8v*)(Wr0 + k0);
        half8v b1 = *(const half8v*)(Wr1 + k0);
        acc2[0][0] = __builtin_amdgcn_mfma_f32_16x16x32_f16(a0, b0, acc2[0][0], 0, 0, 0);
        acc2[0][1] = __builtin_amdgcn_mfma_f32_16x16x32_f16(a0, b1, acc2[0][1], 0, 0, 0);
        acc2[1][0] = __builtin_amdgcn_mfma_f32_16x16x32_f16(a1, b0, acc2[1][0], 0, 0, 0);
        acc2[1][1] = __builtin_amdgcn_mfma_f32_16x16x32_f16(a1, b1, acc2[1][1], 0, 0, 0);
        half8v c0 = *(const half8v*)&aggl[lr][k0 + lk];
        half8v c1 = *(const half8v*)&aggl[16 + lr][k0 + lk];
        half8v d0 = *(const half8v*)(We0 + k0);
        half8v d1 = *(const half8v*)(We1 + k0);
        acc2[0][0] = __builtin_amdgcn_mfma_f32_16x16x32_f16(c0, d0, acc2[0][0], 0, 0, 0);
        acc2[0][1] = __builtin_amdgcn_mfma_f32_16x16x32_f16(c0, d1, acc2[0][1], 0, 0, 0);
        acc2[1][0] = __builtin_amdgcn_mfma_f32_16x16x32_f16(c1, d0, acc2[1][0], 0, 0, 0);
        acc2[1][1] = __builtin_amdgcn_mfma_f32_16x16x32_f16(c1, d1, acc2[1][1], 0, 0, 0);
    }
    int g4 = (lane >> 4) * 4;
    #pragma unroll
    for (int fc = 0; fc < 2; ++fc) {
        int col = col0 + fc * 16 + lr;
        float bv = brel[col];
        #pragma unroll
        for (int fr = 0; fr < 2; ++fr) {
            #pragma unroll
            for (int j = 0; j < 4; ++j) {
                float v = acc2[fr][fc][j] + bv;
                h16[(size_t)(r0 + fr * 16 + g4 + j) * DIM + col] = (_Float16)v;
            }
        }
    }
}

// ---------------- MFMA GEMM (qkv): out16[m,n] = A@W^T + bias ----------------
__global__ __launch_bounds__(256) void gemm_mfma(
    const _Float16* __restrict__ A, const _Float16* __restrict__ W,
    const float* __restrict__ bias, _Float16* __restrict__ outh, int Ncols)
{
    int tid = threadIdx.x;
    int wave = tid >> 6, lane = tid & 63;
    int wm = wave >> 1, wn = wave & 1;
    int row0 = blockIdx.x * 64 + wm * 32;
    int col0 = blockIdx.y * 64 + wn * 32;
    int lr = lane & 15;
    int lk = (lane >> 4) * 8;
    f32x4 zero = {0.f, 0.f, 0.f, 0.f};
    f32x4 acc[2][2] = {{zero, zero}, {zero, zero}};
    const _Float16* Ap0 = A + (size_t)(row0 + lr) * DIM + lk;
    const _Float16* Ap1 = A + (size_t)(row0 + 16 + lr) * DIM + lk;
    const _Float16* Wp0 = W + (size_t)(col0 + lr) * DIM + lk;
    const _Float16* Wp1 = W + (size_t)(col0 + 16 + lr) * DIM + lk;
    #pragma unroll
    for (int k0 = 0; k0 < DIM; k0 += 32) {
        half8v a0 = *(const half8v*)(Ap0 + k0);
        half8v a1 = *(const half8v*)(Ap1 + k0);
        half8v b0 = *(const half8v*)(Wp0 + k0);
        half8v b1 = *(const half8v*)(Wp1 + k0);
        acc[0][0] = __builtin_amdgcn_mfma_f32_16x16x32_f16(a0, b0, acc[0][0], 0, 0, 0);
        acc[0][1] = __builtin_amdgcn_mfma_f32_16x16x32_f16(a0, b1, acc[0][1], 0, 0, 0);
        acc[1][0] = __builtin_amdgcn_mfma_f32_16x16x32_f16(a1, b0, acc[1][0], 0, 0, 0);
        acc[1][1] = __builtin_amdgcn_mfma_f32_16x16x32_f16(a1, b1, acc[1][1], 0, 0, 0);
    }
    int g4 = (lane >> 4) * 4;
    #pragma unroll
    for (int fc = 0; fc < 2; ++fc) {
        int col = col0 + fc * 16 + lr;
        float bv = bias[col];
        #pragma unroll
        for (int fr = 0; fr < 2; ++fr) {
            int rbase = row0 + fr * 16 + g4;
            #pragma unroll
            for (int j = 0; j < 4; ++j) {
                float v = acc[fr][fc][j] + bv;
                outh[(size_t)(rbase + j) * Ncols + col] = (_Float16)v;
            }
        }
    }
}

// ---------------- MFMA GEMM + LayerNorm fused -> f16 x ----------------
__global__ __launch_bounds__(256) void gemm_ln_mfma(
    const _Float16* __restrict__ A, const _Float16* __restrict__ W,
    const float* __restrict__ bias, const float* __restrict__ gamma,
    const float* __restrict__ beta, _Float16* __restrict__ outh)
{
    int tid = threadIdx.x;
    int wave = tid >> 6, lane = tid & 63;
    int row0 = blockIdx.x * 32;
    int col0 = wave * 32;
    int lr = lane & 15;
    int lk = (lane >> 4) * 8;
    f32x4 zero = {0.f, 0.f, 0.f, 0.f};
    f32x4 acc[2][2] = {{zero, zero}, {zero, zero}};
    const _Float16* Ap0 = A + (size_t)(row0 + lr) * DIM + lk;
    const _Float16* Ap1 = A + (size_t)(row0 + 16 + lr) * DIM + lk;
    const _Float16* Wp0 = W + (size_t)(col0 + lr) * DIM + lk;
    const _Float16* Wp1 = W + (size_t)(col0 + 16 + lr) * DIM + lk;
    #pragma unroll
    for (int k0 = 0; k0 < DIM; k0 += 32) {
        half8v a0 = *(const half8v*)(Ap0 + k0);
        half8v a1 = *(const half8v*)(Ap1 + k0);
        half8v b0 = *(const half8v*)(Wp0 + k0);
        half8v b1 = *(const half8v*)(Wp1 + k0);
        acc[0][0] = __builtin_amdgcn_mfma_f32_16x16x32_f16(a0, b0, acc[0][0], 0, 0, 0);
        acc[0][1] = __builtin_amdgcn_mfma_f32_16x16x32_f16(a0, b1, acc[0][1], 0, 0, 0);
        acc[1][0] = __builtin_amdgcn_mfma_f32_16x16x32_f16(a1, b0, acc[1][0], 0, 0, 0);
        acc[1][1] = __builtin_amdgcn_mfma_f32_16x16x32_f16(a1, b1, acc[1][1], 0, 0, 0);
    }
    int g = lane >> 4;
    float v[2][2][4];
    #pragma unroll
    for (int fc = 0; fc < 2; ++fc) {
        float bv = bias[col0 + fc * 16 + lr];
        #pragma unroll
        for (int fr = 0; fr < 2; ++fr)
            #pragma unroll
            for (int j = 0; j < 4; ++j)
                v[fr][fc][j] = acc[fr][fc][j] + bv;
    }
    __shared__ float red_s[32][5];
    __shared__ float red_q[32][5];
    float s[2][4], q[2][4];
    #pragma unroll
    for (int fr = 0; fr < 2; ++fr)
        #pragma unroll
        for (int j = 0; j < 4; ++j) {
            float ss = v[fr][0][j] + v[fr][1][j];
            float qq = v[fr][0][j] * v[fr][0][j] + v[fr][1][j] * v[fr][1][j];
            #pragma unroll
            for (int m = 1; m < 16; m <<= 1) {
                ss += __shfl_xor(ss, m);
                qq += __shfl_xor(qq, m);
            }
            s[fr][j] = ss; q[fr][j] = qq;
        }
    if (lr == 0) {
        #pragma unroll
        for (int fr = 0; fr < 2; ++fr)
            #pragma unroll
            for (int j = 0; j < 4; ++j) {
                red_s[fr * 16 + g * 4 + j][wave] = s[fr][j];
                red_q[fr * 16 + g * 4 + j][wave] = q[fr][j];
            }
    }
    __syncthreads();
    #pragma unroll
    for (int fr = 0; fr < 2; ++fr)
        #pragma unroll
        for (int j = 0; j < 4; ++j) {
            int r = fr * 16 + g * 4 + j;
            float S = red_s[r][0] + red_s[r][1] + red_s[r][2] + red_s[r][3];
            float Q = red_q[r][0] + red_q[r][1] + red_q[r][2] + red_q[r][3];
            float mu = S * (1.0f / 128.0f);
            float inv = rsqrtf(Q * (1.0f / 128.0f) - mu * mu + 1e-5f);
            #pragma unroll
            for (int fc = 0; fc < 2; ++fc) {
                int col = col0 + fc * 16 + lr;
                float o = (v[fr][fc][j] - mu) * inv * gamma[col] + beta[col];
                outh[(size_t)(row0 + r) * DIM + col] = (_Float16)o;
            }
        }
}

// Attention: grid (graph, head, dir); 512 threads = (key-quarter, q-row). f16 qkv.
__global__ __launch_bounds__(512) void attn_kernel(
    const _Float16* __restrict__ qkv, _Float16* __restrict__ o16)
{
    int g = blockIdx.x, h = blockIdx.y, dir = blockIdx.z;
    int qoff  = dir ? N_NODES : 0;
    int kvoff = dir ? 0 : N_NODES;
    int t = threadIdx.x;
    int row = t & 127;
    int qt = t >> 7;                       // key quarter 0..3
    __shared__ float Klds[128][DHEAD];
    __shared__ float Vlds[128][DHEAD];
    __shared__ float Pm[4][128];
    __shared__ float Pl[4][128];
    __shared__ float Pacc[4][128][DHEAD + 1];
    {   // staging: 512 chunks of 8 dims, one per thread
        int r = t >> 2, c = (t & 3) * 8;
        const _Float16* base = qkv + (size_t)(kvoff + g * 128 + r) * (3 * DIM) + DIM + h * DHEAD + c;
        half8v kv = *(const half8v*)(base);
        half8v vv = *(const half8v*)(base + DIM);
        #pragma unroll
        for (int j = 0; j < 8; ++j) {
            Klds[r][c + j] = (float)kv[j];
            Vlds[r][c + j] = (float)vv[j];
        }
    }
    const float scale = 0.17677669529663687f;  // 1/sqrt(32)
    float q[DHEAD];
    const _Float16* qp = qkv + (size_t)(qoff + g * 128 + row) * (3 * DIM) + h * DHEAD;
    #pragma unroll
    for (int j = 0; j < DHEAD; j += 8) {
        half8v qv = *(const half8v*)(qp + j);
        #pragma unroll
        for (int u = 0; u < 8; ++u) q[j + u] = (float)qv[u] * scale;
    }
    __syncthreads();
    int kn0 = qt * 32;
    float s[32];
    float m = -INFINITY;
    #pragma unroll
    for (int i = 0; i < 32; ++i) {
        float d = 0.0f;
        #pragma unroll
        for (int j = 0; j < DHEAD; j += 4) {
            float4 kv = *(const float4*)&Klds[kn0 + i][j];
            d += q[j] * kv.x + q[j+1] * kv.y + q[j+2] * kv.z + q[j+3] * kv.w;
        }
        s[i] = d;
        m = fmaxf(m, d);
    }
    Pm[qt][row] = m;
    __syncthreads();
    float gm = fmaxf(fmaxf(Pm[0][row], Pm[1][row]), fmaxf(Pm[2][row], Pm[3][row]));
    float l = 0.0f;
    float acc[DHEAD];
    #pragma unroll
    for (int j = 0; j < DHEAD; ++j) acc[j] = 0.0f;
    #pragma unroll
    for (int i = 0; i < 32; ++i) {
        float p = __expf(s[i] - gm);
        l += p;
        #pragma unroll
        for (int j = 0; j < DHEAD; j += 4) {
            float4 vv = *(const float4*)&Vlds[kn0 + i][j];
            acc[j]   += p * vv.x;
            acc[j+1] += p * vv.y;
            acc[j+2] += p * vv.z;
            acc[j+3] += p * vv.w;
        }
    }
    Pl[qt][row] = l;
    #pragma unroll
    for (int j = 0; j < DHEAD; ++j) Pacc[qt][row][j] = acc[j];
    __syncthreads();
    if (qt == 0) {
        float linv = 1.0f / (Pl[0][row] + Pl[1][row] + Pl[2][row] + Pl[3][row]);
        _Float16* op = o16 + (size_t)(qoff + g * 128 + row) * DIM + h * DHEAD;
        #pragma unroll
        for (int j = 0; j < DHEAD; ++j) {
            float v = Pacc[0][row][j] + Pacc[1][row][j] + Pacc[2][row][j] + Pacc[3][row][j];
            op[j] = (_Float16)(v * linv);
        }
    }
}

// Fused GlobalAttention pool (both sides, f16 x) + cosine. One block per graph.
__global__ __launch_bounds__(256) void poolcos_kernel(
    const _Float16* __restrict__ x16, const float* __restrict__ gw,
    const float* __restrict__ gb, float* __restrict__ out)
{
    int g = blockIdx.x, t = threadIdx.x;
    int side = t >> 7, r = t & 127;
    __shared__ float sm[2][128];
    __shared__ float al[2][128];
    __shared__ float pl[2][DIM];
    const _Float16* xr = x16 + (size_t)(side * N_NODES + g * 128 + r) * DIM;
    float dot = gb[0];
    #pragma unroll
    for (int d = 0; d < DIM; d += 8) {
        half8v xv = *(const half8v*)(xr + d);
        #pragma unroll
        for (int u = 0; u < 8; ++u) dot += (float)xv[u] * gw[d + u];
    }
    float gate = 1.0f / (1.0f + __expf(-dot));
    sm[side][r] = gate; __syncthreads();
    for (int sN = 64; sN > 0; sN >>= 1) {
        if (r < sN) sm[side][r] = fmaxf(sm[side][r], sm[side][r + sN]);
        __syncthreads();
    }
    float m = sm[side][0]; __syncthreads();
    float e = __expf(gate - m);
    sm[side][r] = e; __syncthreads();
    for (int sN = 64; sN > 0; sN >>= 1) {
        if (r < sN) sm[side][r] += sm[side][r + sN];
        __syncthreads();
    }
    al[side][r] = e / sm[side][0];
    __syncthreads();
    int d = t & 127;
    float acc = 0.0f;
    const _Float16* xg = x16 + (size_t)(side * N_NODES + g * 128) * DIM;
    for (int n = 0; n < 128; ++n) acc += al[side][n] * (float)xg[(size_t)n * DIM + d];
    pl[side][d] = acc;
    __syncthreads();
    if (t < 64) {
        float a0 = pl[0][t], a1 = pl[0][64 + t];
        float b0 = pl[1][t], b1 = pl[1][64 + t];
        float saa = a0 * a0 + a1 * a1;
        float sbb = b0 * b0 + b1 * b1;
        float sab = a0 * b0 + a1 * b1;
        #pragma unroll
        for (int off = 32; off; off >>= 1) {
            saa += __shfl_down(saa, off);
            sbb += __shfl_down(sbb, off);
            sab += __shfl_down(sab, off);
        }
        if (t == 0) {
            float na = fmaxf(sqrtf(saa), 1e-12f);
            float nb = fmaxf(sqrtf(sbb), 1e-12f);
            out[g] = sab / (na * nb);
        }
    }
}

extern "C" void kernel_launch(void* const* d_in, const int* in_sizes, int n_in,
                              void* d_out, int out_size, void* d_ws, size_t ws_size,
                              hipStream_t stream)
{
    const float* x_s    = (const float*)d_in[0];
    const float* x_t    = (const float*)d_in[1];
    const int*   ei_s   = (const int*)d_in[2];
    const float* ea_s   = (const float*)d_in[3];
    const int*   ei_t   = (const int*)d_in[4];
    const float* ea_t   = (const float*)d_in[5];
    const float* rel_w  = (const float*)d_in[8];
    const float* rel_b  = (const float*)d_in[9];
    const float* root_w = (const float*)d_in[10];
    const float* in_w   = (const float*)d_in[11];
    const float* in_b   = (const float*)d_in[12];
    const float* out_w  = (const float*)d_in[13];
    const float* out_b  = (const float*)d_in[14];
    const float* g_ln   = (const float*)d_in[15];
    const float* b_ln   = (const float*)d_in[16];
    const float* gate_w = (const float*)d_in[17];
    const float* gate_b = (const float*)d_in[18];
    float* out = (float*)d_out;

    const size_t RD = (size_t)NROWS * DIM;
    _Float16* h16p = (_Float16*)d_ws;
    _Float16* x16    = h16p; h16p += RD;        // f16 x (conv input / pool)
    _Float16* hb16   = h16p; h16p += RD;        // f16 conv out (qkv A)
    _Float16* qb16   = h16p; h16p += RD * 3;    // f16 qkv
    _Float16* o16    = h16p; h16p += RD;        // f16 attn out (out-proj A)
    _Float16* rel16  = h16p; h16p += (size_t)NLAYER * DIM * DIM;
    _Float16* root16 = h16p; h16p += (size_t)NLAYER * DIM * DIM;
    _Float16* in16   = h16p; h16p += (size_t)NLAYER * 3 * DIM * DIM;
    _Float16* outw16 = h16p; h16p += (size_t)NLAYER * DIM * DIM;
    int* iws = (int*)h16p;
    int* cnt       = iws; iws += 2 * N_NODES;
    int* cursor    = iws; iws += 2 * N_NODES;
    int* row_start = iws; iws += 2 * (N_NODES + 1);
    int* eord      = iws; iws += 2 * NEDGE;

    const int* src_s = ei_s, *dst_s = ei_s + NEDGE;
    const int* src_t = ei_t, *dst_t = ei_t + NEDGE;

    // f16 conversions: x (both sides) + all stacked weights
    {
        dim3 gc(512, 6);
        cvt_kernel<<<gc, 256, 0, stream>>>(x_s, x_t, rel_w, root_w, in_w, out_w,
                                           x16, rel16, root16, in16, outw16);
    }

    // edge counting sort (reused by all layers)
    hipMemsetAsync(cnt, 0, 2 * N_NODES * 4, stream);
    dim3 ge(NEDGE / 256, 2);
    hist_kernel<<<ge, 256, 0, stream>>>(dst_s, dst_t, cnt);
    scan_kernel<<<2, 256, 0, stream>>>(cnt, row_start, cursor);
    reorder_kernel<<<ge, 256, 0, stream>>>(dst_s, dst_t, cursor, eord);

    dim3 g3(NROWS / 64, (3 * DIM) / 64);  // 128 x 6
    dim3 gattn(BGRAPH, NHEAD, 2);

    for (int i = 0; i < NLAYER; ++i) {
        const _Float16* wrel  = rel16  + (size_t)i * DIM * DIM;
        const float*    brel  = rel_b  + (size_t)i * DIM;
        const _Float16* wroot = root16 + (size_t)i * DIM * DIM;
        const _Float16* win   = in16   + (size_t)i * 3 * DIM * DIM;
        const float*    bin   = in_b   + (size_t)i * 3 * DIM;
        const _Float16* wout  = outw16 + (size_t)i * DIM * DIM;
        const float*    bout  = out_b  + (size_t)i * DIM;
        const float*    lg    = g_ln   + (size_t)i * DIM;
        const float*    lb    = b_ln   + (size_t)i * DIM;

        // h = x @ Wroot^T + csr_mean(ew * x[src]) @ Wrel^T + brel
        convagg_kernel<<<NROWS / 32, 256, 0, stream>>>(
            src_s, src_t, ea_s, ea_t, row_start, eord, x16, wroot, wrel, brel, hb16);
        // qkv = h @ Win^T + bin
        gemm_mfma<<<g3, 256, 0, stream>>>(hb16, win, bin, qb16, 3 * DIM);
        attn_kernel<<<gattn, 512, 0, stream>>>(qb16, o16);
        // x = LN(o @ Wout^T + bout)
        gemm_ln_mfma<<<NROWS / 32, 256, 0, stream>>>(o16, wout, bout, lg, lb, x16);
    }

    poolcos_kernel<<<BGRAPH, 256, 0, stream>>>(x16, gate_w, gate_b, out);
}

// Round 6
// 275.782 us; speedup vs baseline: 3.5744x; 1.0767x over previous
//
#include <hip/hip_runtime.h>
#include <math.h>

#define N_NODES 4096
#define NROWS   8192      // both sides stacked
#define BGRAPH  32
#define NEDGE   65536
#define DIM     128
#define NLAYER  4
#define NHEAD   4
#define DHEAD   32

typedef _Float16 half8v __attribute__((ext_vector_type(8)));
typedef _Float16 half2v __attribute__((ext_vector_type(2)));
typedef float f32x4 __attribute__((ext_vector_type(4)));

// ---------------- f16 convert (x + all weights), one dispatch ----------------
__global__ __launch_bounds__(256) void cvt_kernel(
    const float* __restrict__ x_s, const float* __restrict__ x_t,
    const float* __restrict__ rel_w, const float* __restrict__ root_w,
    const float* __restrict__ in_w, const float* __restrict__ out_w,
    _Float16* __restrict__ x16, _Float16* __restrict__ rel16,
    _Float16* __restrict__ root16, _Float16* __restrict__ in16,
    _Float16* __restrict__ outw16)
{
    int seg = blockIdx.y;
    const float* src; _Float16* dst; int n;
    if      (seg == 0) { src = x_s;    dst = x16;            n = N_NODES * DIM; }
    else if (seg == 1) { src = x_t;    dst = x16 + N_NODES * DIM; n = N_NODES * DIM; }
    else if (seg == 2) { src = rel_w;  dst = rel16;          n = NLAYER * DIM * DIM; }
    else if (seg == 3) { src = root_w; dst = root16;         n = NLAYER * DIM * DIM; }
    else if (seg == 4) { src = in_w;   dst = in16;           n = NLAYER * 3 * DIM * DIM; }
    else               { src = out_w;  dst = outw16;         n = NLAYER * DIM * DIM; }
    int i = (blockIdx.x * 256 + threadIdx.x) * 4;
    if (i >= n) return;
    float4 v = *(const float4*)(src + i);
    dst[i]   = (_Float16)v.x;
    dst[i+1] = (_Float16)v.y;
    dst[i+2] = (_Float16)v.z;
    dst[i+3] = (_Float16)v.w;
}

// ---------------- edge counting sort (per side) ----------------
__global__ __launch_bounds__(256) void hist_kernel(
    const int* __restrict__ dst_s, const int* __restrict__ dst_t, int* __restrict__ cnt)
{
    int e = blockIdx.x * 256 + threadIdx.x;
    int side = blockIdx.y;
    const int* d = side ? dst_t : dst_s;
    atomicAdd(&cnt[side * N_NODES + d[e]], 1);
}

__global__ __launch_bounds__(256) void scan_kernel(
    const int* __restrict__ cnt, int* __restrict__ row_start, int* __restrict__ cursor)
{
    int side = blockIdx.x;
    int t = threadIdx.x;
    __shared__ int part[256];
    int local[16];
    int s = 0;
    #pragma unroll
    for (int j = 0; j < 16; ++j) { local[j] = cnt[side * N_NODES + t * 16 + j]; s += local[j]; }
    part[t] = s;
    __syncthreads();
    for (int off = 1; off < 256; off <<= 1) {
        int v = (t >= off) ? part[t - off] : 0;
        __syncthreads();
        part[t] += v;
        __syncthreads();
    }
    int run = (t == 0) ? 0 : part[t - 1];
    #pragma unroll
    for (int j = 0; j < 16; ++j) {
        int idx = t * 16 + j;
        row_start[side * (N_NODES + 1) + idx] = run;
        cursor[side * N_NODES + idx] = run;
        run += local[j];
    }
    if (t == 255) row_start[side * (N_NODES + 1) + N_NODES] = run;
}

__global__ __launch_bounds__(256) void reorder_kernel(
    const int* __restrict__ dst_s, const int* __restrict__ dst_t,
    int* __restrict__ cursor, int* __restrict__ eord)
{
    int e = blockIdx.x * 256 + threadIdx.x;
    int side = blockIdx.y;
    const int* d = side ? dst_t : dst_s;
    int pos = atomicAdd(&cursor[side * N_NODES + d[e]], 1);
    eord[side * NEDGE + pos] = e;
}

// One-time: materialize edge_attr in dst-sorted order as f16, plus sorted src.
// Block = 16 edges x 16 threads (8 dims each).
__global__ __launch_bounds__(256) void gather_ea_kernel(
    const int* __restrict__ src_s, const int* __restrict__ src_t,
    const float* __restrict__ ea_s, const float* __restrict__ ea_t,
    const int* __restrict__ eord,
    _Float16* __restrict__ ea16s, int* __restrict__ srcs)
{
    int side = blockIdx.y;
    int t = threadIdx.x;
    int p = blockIdx.x * 16 + (t >> 4);      // sorted position
    int sub = t & 15;
    const int* eo = eord + side * NEDGE;
    const int* sarr = side ? src_t : src_s;
    const float* ea = side ? ea_t : ea_s;
    int e = eo[p];
    if (sub == 0) srcs[side * NEDGE + p] = sarr[e];
    const float* sp = ea + (size_t)e * DIM + sub * 8;
    float4 v0 = *(const float4*)(sp);
    float4 v1 = *(const float4*)(sp + 4);
    half8v h;
    h[0] = (_Float16)v0.x; h[1] = (_Float16)v0.y; h[2] = (_Float16)v0.z; h[3] = (_Float16)v0.w;
    h[4] = (_Float16)v1.x; h[5] = (_Float16)v1.y; h[6] = (_Float16)v1.z; h[7] = (_Float16)v1.w;
    *(half8v*)(ea16s + (size_t)(side * NEDGE + p) * DIM + sub * 8) = h;
}

// CSR mean-aggregate: one wave per node, streams sorted f16 edge rows.
// agg16[side*N+n,:] = (f16) mean_e ea16s[i,:] * x16[srcs[i],:]
__global__ __launch_bounds__(64) void agg_kernel(
    const int* __restrict__ srcs, const _Float16* __restrict__ ea16s,
    const int* __restrict__ row_start,
    const _Float16* __restrict__ x16, _Float16* __restrict__ agg16)
{
    int n = blockIdx.x, side = blockIdx.y;
    int lane = threadIdx.x;
    const int* sp = srcs + side * NEDGE;
    const _Float16* ep = ea16s + (size_t)side * NEDGE * DIM + lane * 2;
    const _Float16* xp = x16 + (size_t)side * N_NODES * DIM + lane * 2;
    int rs = row_start[side * (N_NODES + 1) + n];
    int re = row_start[side * (N_NODES + 1) + n + 1];
    float ax = 0.f, ay = 0.f;
    for (int i = rs; i < re; ++i) {
        int s = sp[i];
        half2v w = *(const half2v*)(ep + (size_t)i * DIM);
        half2v xv = *(const half2v*)(xp + (size_t)s * DIM);
        ax += (float)w[0] * (float)xv[0];
        ay += (float)w[1] * (float)xv[1];
    }
    float sc = 1.0f / (float)max(re - rs, 1);
    half2v o; o[0] = (_Float16)(ax * sc); o[1] = (_Float16)(ay * sc);
    *(half2v*)(agg16 + (size_t)(side * N_NODES + n) * DIM + lane * 2) = o;
}

// ---------------- dual-source MFMA GEMM (conv): h = A1@W1^T + A2@W2^T + bias
__global__ __launch_bounds__(256) void gemm2_mfma(
    const _Float16* __restrict__ A1, const _Float16* __restrict__ W1,
    const _Float16* __restrict__ A2, const _Float16* __restrict__ W2,
    const float* __restrict__ bias, _Float16* __restrict__ outh)
{
    int tid = threadIdx.x;
    int wave = tid >> 6, lane = tid & 63;
    int wm = wave >> 1, wn = wave & 1;
    int row0 = blockIdx.x * 64 + wm * 32;
    int col0 = blockIdx.y * 64 + wn * 32;
    int lr = lane & 15;
    int lk = (lane >> 4) * 8;
    f32x4 zero = {0.f, 0.f, 0.f, 0.f};
    f32x4 acc[2][2] = {{zero, zero}, {zero, zero}};
    #pragma unroll
    for (int s = 0; s < 2; ++s) {
        const _Float16* A = s ? A2 : A1;
        const _Float16* W = s ? W2 : W1;
        const _Float16* Ap0 = A + (size_t)(row0 + lr) * DIM + lk;
        const _Float16* Ap1 = A + (size_t)(row0 + 16 + lr) * DIM + lk;
        const _Float16* Wp0 = W + (size_t)(col0 + lr) * DIM + lk;
        const _Float16* Wp1 = W + (size_t)(col0 + 16 + lr) * DIM + lk;
        #pragma unroll
        for (int k0 = 0; k0 < DIM; k0 += 32) {
            half8v a0 = *(const half8v*)(Ap0 + k0);
            half8v a1 = *(const half8v*)(Ap1 + k0);
            half8v b0 = *(const half8v*)(Wp0 + k0);
            half8v b1 = *(const half8v*)(Wp1 + k0);
            acc[0][0] = __builtin_amdgcn_mfma_f32_16x16x32_f16(a0, b0, acc[0][0], 0, 0, 0);
            acc[0][1] = __builtin_amdgcn_mfma_f32_16x16x32_f16(a0, b1, acc[0][1], 0, 0, 0);
            acc[1][0] = __builtin_amdgcn_mfma_f32_16x16x32_f16(a1, b0, acc[1][0], 0, 0, 0);
            acc[1][1] = __builtin_amdgcn_mfma_f32_16x16x32_f16(a1, b1, acc[1][1], 0, 0, 0);
        }
    }
    int g4 = (lane >> 4) * 4;
    #pragma unroll
    for (int fc = 0; fc < 2; ++fc) {
        int col = col0 + fc * 16 + lr;
        float bv = bias[col];
        #pragma unroll
        for (int fr = 0; fr < 2; ++fr) {
            int rbase = row0 + fr * 16 + g4;
            #pragma unroll
            for (int j = 0; j < 4; ++j) {
                float v = acc[fr][fc][j] + bv;
                outh[(size_t)(rbase + j) * DIM + col] = (_Float16)v;
            }
        }
    }
}

// ---------------- MFMA GEMM (qkv): out16[m,n] = A@W^T + bias ----------------
__global__ __launch_bounds__(256) void gemm_mfma(
    const _Float16* __restrict__ A, const _Float16* __restrict__ W,
    const float* __restrict__ bias, _Float16* __restrict__ outh, int Ncols)
{
    int tid = threadIdx.x;
    int wave = tid >> 6, lane = tid & 63;
    int wm = wave >> 1, wn = wave & 1;
    int row0 = blockIdx.x * 64 + wm * 32;
    int col0 = blockIdx.y * 64 + wn * 32;
    int lr = lane & 15;
    int lk = (lane >> 4) * 8;
    f32x4 zero = {0.f, 0.f, 0.f, 0.f};
    f32x4 acc[2][2] = {{zero, zero}, {zero, zero}};
    const _Float16* Ap0 = A + (size_t)(row0 + lr) * DIM + lk;
    const _Float16* Ap1 = A + (size_t)(row0 + 16 + lr) * DIM + lk;
    const _Float16* Wp0 = W + (size_t)(col0 + lr) * DIM + lk;
    const _Float16* Wp1 = W + (size_t)(col0 + 16 + lr) * DIM + lk;
    #pragma unroll
    for (int k0 = 0; k0 < DIM; k0 += 32) {
        half8v a0 = *(const half8v*)(Ap0 + k0);
        half8v a1 = *(const half8v*)(Ap1 + k0);
        half8v b0 = *(const half8v*)(Wp0 + k0);
        half8v b1 = *(const half8v*)(Wp1 + k0);
        acc[0][0] = __builtin_amdgcn_mfma_f32_16x16x32_f16(a0, b0, acc[0][0], 0, 0, 0);
        acc[0][1] = __builtin_amdgcn_mfma_f32_16x16x32_f16(a0, b1, acc[0][1], 0, 0, 0);
        acc[1][0] = __builtin_amdgcn_mfma_f32_16x16x32_f16(a1, b0, acc[1][0], 0, 0, 0);
        acc[1][1] = __builtin_amdgcn_mfma_f32_16x16x32_f16(a1, b1, acc[1][1], 0, 0, 0);
    }
    int g4 = (lane >> 4) * 4;
    #pragma unroll
    for (int fc = 0; fc < 2; ++fc) {
        int col = col0 + fc * 16 + lr;
        float bv = bias[col];
        #pragma unroll
        for (int fr = 0; fr < 2; ++fr) {
            int rbase = row0 + fr * 16 + g4;
            #pragma unroll
            for (int j = 0; j < 4; ++j) {
                float v = acc[fr][fc][j] + bv;
                outh[(size_t)(rbase + j) * Ncols + col] = (_Float16)v;
            }
        }
    }
}

// ---------------- MFMA GEMM + LayerNorm fused -> f16 x ----------------
__global__ __launch_bounds__(256) void gemm_ln_mfma(
    const _Float16* __restrict__ A, const _Float16* __restrict__ W,
    const float* __restrict__ bias, const float* __restrict__ gamma,
    const float* __restrict__ beta, _Float16* __restrict__ outh)
{
    int tid = threadIdx.x;
    int wave = tid >> 6, lane = tid & 63;
    int row0 = blockIdx.x * 32;
    int col0 = wave * 32;
    int lr = lane & 15;
    int lk = (lane >> 4) * 8;
    f32x4 zero = {0.f, 0.f, 0.f, 0.f};
    f32x4 acc[2][2] = {{zero, zero}, {zero, zero}};
    const _Float16* Ap0 = A + (size_t)(row0 + lr) * DIM + lk;
    const _Float16* Ap1 = A + (size_t)(row0 + 16 + lr) * DIM + lk;
    const _Float16* Wp0 = W + (size_t)(col0 + lr) * DIM + lk;
    const _Float16* Wp1 = W + (size_t)(col0 + 16 + lr) * DIM + lk;
    #pragma unroll
    for (int k0 = 0; k0 < DIM; k0 += 32) {
        half8v a0 = *(const half8v*)(Ap0 + k0);
        half8v a1 = *(const half8v*)(Ap1 + k0);
        half8v b0 = *(const half8v*)(Wp0 + k0);
        half8v b1 = *(const half8v*)(Wp1 + k0);
        acc[0][0] = __builtin_amdgcn_mfma_f32_16x16x32_f16(a0, b0, acc[0][0], 0, 0, 0);
        acc[0][1] = __builtin_amdgcn_mfma_f32_16x16x32_f16(a0, b1, acc[0][1], 0, 0, 0);
        acc[1][0] = __builtin_amdgcn_mfma_f32_16x16x32_f16(a1, b0, acc[1][0], 0, 0, 0);
        acc[1][1] = __builtin_amdgcn_mfma_f32_16x16x32_f16(a1, b1, acc[1][1], 0, 0, 0);
    }
    int g = lane >> 4;
    float v[2][2][4];
    #pragma unroll
    for (int fc = 0; fc < 2; ++fc) {
        float bv = bias[col0 + fc * 16 + lr];
        #pragma unroll
        for (int fr = 0; fr < 2; ++fr)
            #pragma unroll
            for (int j = 0; j < 4; ++j)
                v[fr][fc][j] = acc[fr][fc][j] + bv;
    }
    __shared__ float red_s[32][5];
    __shared__ float red_q[32][5];
    float s[2][4], q[2][4];
    #pragma unroll
    for (int fr = 0; fr < 2; ++fr)
        #pragma unroll
        for (int j = 0; j < 4; ++j) {
            float ss = v[fr][0][j] + v[fr][1][j];
            float qq = v[fr][0][j] * v[fr][0][j] + v[fr][1][j] * v[fr][1][j];
            #pragma unroll
            for (int m = 1; m < 16; m <<= 1) {
                ss += __shfl_xor(ss, m);
                qq += __shfl_xor(qq, m);
            }
            s[fr][j] = ss; q[fr][j] = qq;
        }
    if (lr == 0) {
        #pragma unroll
        for (int fr = 0; fr < 2; ++fr)
            #pragma unroll
            for (int j = 0; j < 4; ++j) {
                red_s[fr * 16 + g * 4 + j][wave] = s[fr][j];
                red_q[fr * 16 + g * 4 + j][wave] = q[fr][j];
            }
    }
    __syncthreads();
    #pragma unroll
    for (int fr = 0; fr < 2; ++fr)
        #pragma unroll
        for (int j = 0; j < 4; ++j) {
            int r = fr * 16 + g * 4 + j;
            float S = red_s[r][0] + red_s[r][1] + red_s[r][2] + red_s[r][3];
            float Q = red_q[r][0] + red_q[r][1] + red_q[r][2] + red_q[r][3];
            float mu = S * (1.0f / 128.0f);
            float inv = rsqrtf(Q * (1.0f / 128.0f) - mu * mu + 1e-5f);
            #pragma unroll
            for (int fc = 0; fc < 2; ++fc) {
                int col = col0 + fc * 16 + lr;
                float o = (v[fr][fc][j] - mu) * inv * gamma[col] + beta[col];
                outh[(size_t)(row0 + r) * DIM + col] = (_Float16)o;
            }
        }
}

// Attention: grid (graph, head, dir); 512 threads = (key-quarter, q-row). f16 qkv.
__global__ __launch_bounds__(512) void attn_kernel(
    const _Float16* __restrict__ qkv, _Float16* __restrict__ o16)
{
    int g = blockIdx.x, h = blockIdx.y, dir = blockIdx.z;
    int qoff  = dir ? N_NODES : 0;
    int kvoff = dir ? 0 : N_NODES;
    int t = threadIdx.x;
    int row = t & 127;
    int qt = t >> 7;                       // key quarter 0..3
    __shared__ float Klds[128][DHEAD];
    __shared__ float Vlds[128][DHEAD];
    __shared__ float Pm[4][128];
    __shared__ float Pl[4][128];
    __shared__ float Pacc[4][128][DHEAD + 1];
    {   // staging: 512 chunks of 8 dims, one per thread
        int r = t >> 2, c = (t & 3) * 8;
        const _Float16* base = qkv + (size_t)(kvoff + g * 128 + r) * (3 * DIM) + DIM + h * DHEAD + c;
        half8v kv = *(const half8v*)(base);
        half8v vv = *(const half8v*)(base + DIM);
        #pragma unroll
        for (int j = 0; j < 8; ++j) {
            Klds[r][c + j] = (float)kv[j];
            Vlds[r][c + j] = (float)vv[j];
        }
    }
    const float scale = 0.17677669529663687f;  // 1/sqrt(32)
    float q[DHEAD];
    const _Float16* qp = qkv + (size_t)(qoff + g * 128 + row) * (3 * DIM) + h * DHEAD;
    #pragma unroll
    for (int j = 0; j < DHEAD; j += 8) {
        half8v qv = *(const half8v*)(qp + j);
        #pragma unroll
        for (int u = 0; u < 8; ++u) q[j + u] = (float)qv[u] * scale;
    }
    __syncthreads();
    int kn0 = qt * 32;
    float s[32];
    float m = -INFINITY;
    #pragma unroll
    for (int i = 0; i < 32; ++i) {
        float d = 0.0f;
        #pragma unroll
        for (int j = 0; j < DHEAD; j += 4) {
            float4 kv = *(const float4*)&Klds[kn0 + i][j];
            d += q[j] * kv.x + q[j+1] * kv.y + q[j+2] * kv.z + q[j+3] * kv.w;
        }
        s[i] = d;
        m = fmaxf(m, d);
    }
    Pm[qt][row] = m;
    __syncthreads();
    float gm = fmaxf(fmaxf(Pm[0][row], Pm[1][row]), fmaxf(Pm[2][row], Pm[3][row]));
    float l = 0.0f;
    float acc[DHEAD];
    #pragma unroll
    for (int j = 0; j < DHEAD; ++j) acc[j] = 0.0f;
    #pragma unroll
    for (int i = 0; i < 32; ++i) {
        float p = __expf(s[i] - gm);
        l += p;
        #pragma unroll
        for (int j = 0; j < DHEAD; j += 4) {
            float4 vv = *(const float4*)&Vlds[kn0 + i][j];
            acc[j]   += p * vv.x;
            acc[j+1] += p * vv.y;
            acc[j+2] += p * vv.z;
            acc[j+3] += p * vv.w;
        }
    }
    Pl[qt][row] = l;
    #pragma unroll
    for (int j = 0; j < DHEAD; ++j) Pacc[qt][row][j] = acc[j];
    __syncthreads();
    if (qt == 0) {
        float linv = 1.0f / (Pl[0][row] + Pl[1][row] + Pl[2][row] + Pl[3][row]);
        _Float16* op = o16 + (size_t)(qoff + g * 128 + row) * DIM + h * DHEAD;
        #pragma unroll
        for (int j = 0; j < DHEAD; ++j) {
            float v = Pacc[0][row][j] + Pacc[1][row][j] + Pacc[2][row][j] + Pacc[3][row][j];
            op[j] = (_Float16)(v * linv);
        }
    }
}

// Fused GlobalAttention pool (both sides, f16 x) + cosine. One block per graph.
__global__ __launch_bounds__(256) void poolcos_kernel(
    const _Float16* __restrict__ x16, const float* __restrict__ gw,
    const float* __restrict__ gb, float* __restrict__ out)
{
    int g = blockIdx.x, t = threadIdx.x;
    int side = t >> 7, r = t & 127;
    __shared__ float sm[2][128];
    __shared__ float al[2][128];
    __shared__ float pl[2][DIM];
    const _Float16* xr = x16 + (size_t)(side * N_NODES + g * 128 + r) * DIM;
    float dot = gb[0];
    #pragma unroll
    for (int d = 0; d < DIM; d += 8) {
        half8v xv = *(const half8v*)(xr + d);
        #pragma unroll
        for (int u = 0; u < 8; ++u) dot += (float)xv[u] * gw[d + u];
    }
    float gate = 1.0f / (1.0f + __expf(-dot));
    sm[side][r] = gate; __syncthreads();
    for (int sN = 64; sN > 0; sN >>= 1) {
        if (r < sN) sm[side][r] = fmaxf(sm[side][r], sm[side][r + sN]);
        __syncthreads();
    }
    float m = sm[side][0]; __syncthreads();
    float e = __expf(gate - m);
    sm[side][r] = e; __syncthreads();
    for (int sN = 64; sN > 0; sN >>= 1) {
        if (r < sN) sm[side][r] += sm[side][r + sN];
        __syncthreads();
    }
    al[side][r] = e / sm[side][0];
    __syncthreads();
    int d = t & 127;
    float acc = 0.0f;
    const _Float16* xg = x16 + (size_t)(side * N_NODES + g * 128) * DIM;
    for (int n = 0; n < 128; ++n) acc += al[side][n] * (float)xg[(size_t)n * DIM + d];
    pl[side][d] = acc;
    __syncthreads();
    if (t < 64) {
        float a0 = pl[0][t], a1 = pl[0][64 + t];
        float b0 = pl[1][t], b1 = pl[1][64 + t];
        float saa = a0 * a0 + a1 * a1;
        float sbb = b0 * b0 + b1 * b1;
        float sab = a0 * b0 + a1 * b1;
        #pragma unroll
        for (int off = 32; off; off >>= 1) {
            saa += __shfl_down(saa, off);
            sbb += __shfl_down(sbb, off);
            sab += __shfl_down(sab, off);
        }
        if (t == 0) {
            float na = fmaxf(sqrtf(saa), 1e-12f);
            float nb = fmaxf(sqrtf(sbb), 1e-12f);
            out[g] = sab / (na * nb);
        }
    }
}

extern "C" void kernel_launch(void* const* d_in, const int* in_sizes, int n_in,
                              void* d_out, int out_size, void* d_ws, size_t ws_size,
                              hipStream_t stream)
{
    const float* x_s    = (const float*)d_in[0];
    const float* x_t    = (const float*)d_in[1];
    const int*   ei_s   = (const int*)d_in[2];
    const float* ea_s   = (const float*)d_in[3];
    const int*   ei_t   = (const int*)d_in[4];
    const float* ea_t   = (const float*)d_in[5];
    const float* rel_w  = (const float*)d_in[8];
    const float* rel_b  = (const float*)d_in[9];
    const float* root_w = (const float*)d_in[10];
    const float* in_w   = (const float*)d_in[11];
    const float* in_b   = (const float*)d_in[12];
    const float* out_w  = (const float*)d_in[13];
    const float* out_b  = (const float*)d_in[14];
    const float* g_ln   = (const float*)d_in[15];
    const float* b_ln   = (const float*)d_in[16];
    const float* gate_w = (const float*)d_in[17];
    const float* gate_b = (const float*)d_in[18];
    float* out = (float*)d_out;

    const size_t RD = (size_t)NROWS * DIM;
    _Float16* h16p = (_Float16*)d_ws;
    _Float16* x16    = h16p; h16p += RD;        // f16 x (conv input / pool)
    _Float16* agg16  = h16p; h16p += RD;        // f16 mean-aggregate
    _Float16* hb16   = h16p; h16p += RD;        // f16 conv out (qkv A)
    _Float16* qb16   = h16p; h16p += RD * 3;    // f16 qkv
    _Float16* o16    = h16p; h16p += RD;        // f16 attn out (out-proj A)
    _Float16* ea16s  = h16p; h16p += (size_t)2 * NEDGE * DIM;  // sorted f16 edge attr
    _Float16* rel16  = h16p; h16p += (size_t)NLAYER * DIM * DIM;
    _Float16* root16 = h16p; h16p += (size_t)NLAYER * DIM * DIM;
    _Float16* in16   = h16p; h16p += (size_t)NLAYER * 3 * DIM * DIM;
    _Float16* outw16 = h16p; h16p += (size_t)NLAYER * DIM * DIM;
    int* iws = (int*)h16p;
    int* cnt       = iws; iws += 2 * N_NODES;
    int* cursor    = iws; iws += 2 * N_NODES;
    int* row_start = iws; iws += 2 * (N_NODES + 1);
    int* eord      = iws; iws += 2 * NEDGE;
    int* srcs      = iws; iws += 2 * NEDGE;     // sorted src indices

    const int* src_s = ei_s, *dst_s = ei_s + NEDGE;
    const int* src_t = ei_t, *dst_t = ei_t + NEDGE;

    // f16 conversions: x (both sides) + all stacked weights
    {
        dim3 gc(512, 6);
        cvt_kernel<<<gc, 256, 0, stream>>>(x_s, x_t, rel_w, root_w, in_w, out_w,
                                           x16, rel16, root16, in16, outw16);
    }

    // edge counting sort + sorted f16 edge-attr materialization (once)
    hipMemsetAsync(cnt, 0, 2 * N_NODES * 4, stream);
    dim3 ge(NEDGE / 256, 2);
    hist_kernel<<<ge, 256, 0, stream>>>(dst_s, dst_t, cnt);
    scan_kernel<<<2, 256, 0, stream>>>(cnt, row_start, cursor);
    reorder_kernel<<<ge, 256, 0, stream>>>(dst_s, dst_t, cursor, eord);
    {
        dim3 gg(NEDGE / 16, 2);
        gather_ea_kernel<<<gg, 256, 0, stream>>>(src_s, src_t, ea_s, ea_t,
                                                 eord, ea16s, srcs);
    }

    dim3 g1(NROWS / 64, DIM / 64);        // 128 x 2
    dim3 g3(NROWS / 64, (3 * DIM) / 64);  // 128 x 6
    dim3 gagg(N_NODES, 2);
    dim3 gattn(BGRAPH, NHEAD, 2);

    for (int i = 0; i < NLAYER; ++i) {
        const _Float16* wrel  = rel16  + (size_t)i * DIM * DIM;
        const float*    brel  = rel_b  + (size_t)i * DIM;
        const _Float16* wroot = root16 + (size_t)i * DIM * DIM;
        const _Float16* win   = in16   + (size_t)i * 3 * DIM * DIM;
        const float*    bin   = in_b   + (size_t)i * 3 * DIM;
        const _Float16* wout  = outw16 + (size_t)i * DIM * DIM;
        const float*    bout  = out_b  + (size_t)i * DIM;
        const float*    lg    = g_ln   + (size_t)i * DIM;
        const float*    lb    = b_ln   + (size_t)i * DIM;

        // mean aggregate (CSR, streaming sorted f16 edges)
        agg_kernel<<<gagg, 64, 0, stream>>>(srcs, ea16s, row_start, x16, agg16);
        // h = x @ Wroot^T + agg @ Wrel^T + brel
        gemm2_mfma<<<g1, 256, 0, stream>>>(x16, wroot, agg16, wrel, brel, hb16);
        // qkv = h @ Win^T + bin
        gemm_mfma<<<g3, 256, 0, stream>>>(hb16, win, bin, qb16, 3 * DIM);
        attn_kernel<<<gattn, 512, 0, stream>>>(qb16, o16);
        // x = LN(o @ Wout^T + bout)
        gemm_ln_mfma<<<NROWS / 32, 256, 0, stream>>>(o16, wout, bout, lg, lb, x16);
    }

    poolcos_kernel<<<BGRAPH, 256, 0, stream>>>(x16, gate_w, gate_b, out);
}